// Round 1
// baseline (1792.601 us; speedup 1.0000x reference)
//
#include <hip/hip_runtime.h>

#define BB    16384
#define SS    200
#define NF    6
#define HH    50
#define TT    5
#define G4    200      // 4*H
#define KD    56       // NF + HH
#define ROWS  64       // batch rows per block (one per lane)
#define NWAVE 8        // unit-groups (one per wave)
#define NU    7        // units per wave (8*7=56 slots, 50 real + 6 phantom)
#define BLK   (ROWS * NWAVE)   // 512 threads

__device__ __forceinline__ float sigm(float x) {
    return 1.0f / (1.0f + __expf(-x));
}
__device__ __forceinline__ float tanh_f(float x) {
    // 2*sigmoid(2x)-1; saturates correctly for large |x|
    return 2.0f / (1.0f + __expf(-2.0f * x)) - 1.0f;
}

// Stage [Wih | Whh] rows into Wc[208][56] (rows 200..207 zeroed for phantom
// units) and bs = bih + bhh (bs[200..207] zeroed).
__device__ __forceinline__ void stage_w(const float* __restrict__ Wih,
                                        const float* __restrict__ Whh,
                                        const float* __restrict__ bih,
                                        const float* __restrict__ bhh,
                                        float* Wc, float* bs, int tid)
{
    for (int idx = tid; idx < G4 * NF; idx += BLK) {
        int j = idx / NF, k = idx - j * NF;
        Wc[j * KD + k] = Wih[idx];
    }
    for (int idx = tid; idx < G4 * HH; idx += BLK) {
        int j = idx / HH, k = idx - j * HH;
        Wc[j * KD + NF + k] = Whh[idx];
    }
    for (int idx = tid; idx < 8 * KD; idx += BLK)
        Wc[G4 * KD + idx] = 0.0f;
    for (int idx = tid; idx < G4; idx += BLK)
        bs[idx] = bih[idx] + bhh[idx];
    if (tid < 8) bs[G4 + tid] = 0.0f;
}

__global__ __launch_bounds__(BLK, 1) void lstm_fused(
    const float* __restrict__ seq,
    const float* __restrict__ Wih_e, const float* __restrict__ Whh_e,
    const float* __restrict__ bih_e, const float* __restrict__ bhh_e,
    const float* __restrict__ Wih_d, const float* __restrict__ Whh_d,
    const float* __restrict__ bih_d, const float* __restrict__ bhh_d,
    const float* __restrict__ Wl, const float* __restrict__ bl,
    float* __restrict__ out)
{
    __shared__ float Wc[208 * KD];      // 46592 B  weights [x|h] per gate-row
    __shared__ float bs[208];           //   832 B  fused bias
    __shared__ float hbuf[HH * ROWS];   // 12800 B  h exchange: [unit][row]
    __shared__ float Wls[NF * HH];      //  1200 B  output layer
    __shared__ float bls[NF];

    const int tid  = threadIdx.x;
    const int w    = tid >> 6;          // wave id = unit group
    const int row  = tid & 63;          // lane = batch row within block
    const int grow = blockIdx.x * ROWS + row;
    const int ub   = w * NU;

    stage_w(Wih_e, Whh_e, bih_e, bhh_e, Wc, bs, tid);
    for (int idx = tid; idx < NF * HH; idx += BLK) Wls[idx] = Wl[idx];
    if (tid < NF) bls[tid] = bl[tid];
    __syncthreads();

    float xh[KD];   // [x(6) | h(50)] for this lane's row — registers
    float c[NU];    // cell state for this wave's units
    #pragma unroll
    for (int i = 0; i < NU; ++i) c[i] = 0.0f;
    #pragma unroll
    for (int k = 0; k < KD; ++k) xh[k] = 0.0f;

    const float* xp = seq + (size_t)grow * (SS * NF);
    float*       op = out + (size_t)grow * (TT * NF);

    for (int t = 0; t < SS + TT; ++t) {
        if (t == SS) {
            // swap to decoder weights (all prior Wc reads are behind the
            // step-final barrier of t = SS-1)
            __syncthreads();
            stage_w(Wih_d, Whh_d, bih_d, bhh_d, Wc, bs, tid);
            __syncthreads();
        }
        if (t < SS) {
            #pragma unroll
            for (int n = 0; n < NF; ++n) xh[n] = xp[t * NF + n];
            // at t==SS, xh[0..5] still holds x_{S-1} == dec_in; in decoder
            // steps it holds the previous prediction.
        }

        // ---- gates + cell update for this wave's units ----
        #pragma unroll
        for (int i = 0; i < NU; ++i) {
            const int u = ub + i;                     // wave-uniform
            const float* wi = &Wc[(u)        * KD];   // broadcast LDS reads
            const float* wf = &Wc[(HH  + u)  * KD];
            const float* wg = &Wc[(2*HH + u) * KD];
            const float* wo = &Wc[(3*HH + u) * KD];
            float ai = bs[u], af = bs[HH + u], ag = bs[2*HH + u], ao = bs[3*HH + u];
            #pragma unroll
            for (int k = 0; k < KD; ++k) {
                const float xv = xh[k];
                ai = fmaf(wi[k], xv, ai);
                af = fmaf(wf[k], xv, af);
                ag = fmaf(wg[k], xv, ag);
                ao = fmaf(wo[k], xv, ao);
            }
            const float cc = sigm(af) * c[i] + sigm(ai) * tanh_f(ag);
            c[i] = cc;
            const float hh = sigm(ao) * tanh_f(cc);
            if (u < HH) hbuf[u * ROWS + row] = hh;    // consecutive banks
        }
        __syncthreads();
        #pragma unroll
        for (int j = 0; j < HH; ++j) xh[NF + j] = hbuf[j * ROWS + row];
        __syncthreads();

        // ---- decoder: prediction = h @ Wl^T + bl (redundant per wave) ----
        if (t >= SS) {
            float pr[NF];
            #pragma unroll
            for (int n = 0; n < NF; ++n) {
                float a = bls[n];
                #pragma unroll
                for (int u2 = 0; u2 < HH; ++u2)
                    a = fmaf(Wls[n * HH + u2], xh[NF + u2], a);
                pr[n] = a;
            }
            if (w == 0) {
                #pragma unroll
                for (int n = 0; n < NF; ++n) op[(t - SS) * NF + n] = pr[n];
            }
            #pragma unroll
            for (int n = 0; n < NF; ++n) xh[n] = pr[n];   // next decoder input
        }
    }
}

extern "C" void kernel_launch(void* const* d_in, const int* in_sizes, int n_in,
                              void* d_out, int out_size, void* d_ws, size_t ws_size,
                              hipStream_t stream)
{
    const float* seq   = (const float*)d_in[0];
    const float* Wih_e = (const float*)d_in[1];
    const float* Whh_e = (const float*)d_in[2];
    const float* bih_e = (const float*)d_in[3];
    const float* bhh_e = (const float*)d_in[4];
    const float* Wih_d = (const float*)d_in[5];
    const float* Whh_d = (const float*)d_in[6];
    const float* bih_d = (const float*)d_in[7];
    const float* bhh_d = (const float*)d_in[8];
    const float* Wl    = (const float*)d_in[9];
    const float* bl    = (const float*)d_in[10];
    float* out = (float*)d_out;

    dim3 grid(BB / ROWS);   // 256 blocks -> 1 per CU
    dim3 block(BLK);        // 512 threads = 8 waves x 64 rows
    lstm_fused<<<grid, block, 0, stream>>>(seq, Wih_e, Whh_e, bih_e, bhh_e,
                                           Wih_d, Whh_d, bih_d, bhh_d,
                                           Wl, bl, out);
}

// Round 2
// 807.641 us; speedup vs baseline: 2.2196x; 2.2196x over previous
//
#include <hip/hip_runtime.h>

#define BB 16384
#define SS 200
#define NF 6
#define HH 50
#define TT 5
#define ROWS 64
#define BLK 512
#define SEQ_STRIDE (SS * NF)   // 1200

typedef __attribute__((ext_vector_type(8))) short short8;
typedef __attribute__((ext_vector_type(4))) float f32x4;

__device__ __forceinline__ unsigned short f2bf(float f) {
    unsigned u = __float_as_uint(f);
    u += 0x7FFF + ((u >> 16) & 1);          // round-to-nearest-even
    return (unsigned short)(u >> 16);
}
__device__ __forceinline__ float bf2f(unsigned short h) {
    return __uint_as_float(((unsigned)h) << 16);
}
__device__ __forceinline__ float sigm(float x)  { return 1.0f / (1.0f + __expf(-x)); }
__device__ __forceinline__ float tanh_f(float x){ return 2.0f / (1.0f + __expf(-2.0f*x)) - 1.0f; }

// Pack weights into A-fragment order for mfma_f32_16x16x32_bf16, split hi/lo.
// Logical A[g2][k]: g2 = 4*u + gate (gate-interleaved, 256 rows: u<50 real),
// k = [x(0..5) | h(6..55) | pad(56..63)].
// Frag layout: tile (mt,ks): lane l holds A[mt*16 + (l&15)][ks*32 + (l>>4)*8 + j],
// stored at ushort index ((mt*2+ks)*64 + l)*8 + j  (lane-consecutive 16B chunks).
__device__ __forceinline__ void stage_weights(
    const float* __restrict__ Wih, const float* __restrict__ Whh,
    const float* __restrict__ bih, const float* __restrict__ bhh,
    unsigned short* WhU, unsigned short* WlU, float* bs, int tid)
{
    for (int idx = tid; idx < 256 * 64; idx += BLK) {
        int g2 = idx >> 6, k = idx & 63;
        int u = g2 >> 2, gt = g2 & 3;
        float v = 0.0f;
        if (u < HH) {
            int orow = gt * HH + u;                 // original gate-row
            if (k < NF)           v = Wih[orow * NF + k];
            else if (k < NF + HH) v = Whh[orow * HH + (k - NF)];
        }
        unsigned short hb = f2bf(v);
        unsigned short lb = f2bf(v - bf2f(hb));
        int mt = g2 >> 4, r = g2 & 15, ks = k >> 5, kt = (k >> 3) & 3, j = k & 7;
        int pos = (((mt * 2 + ks) * 64) + kt * 16 + r) * 8 + j;
        WhU[pos] = hb; WlU[pos] = lb;
    }
    for (int g2 = tid; g2 < 256; g2 += BLK) {
        int u = g2 >> 2, gt = g2 & 3;
        bs[g2] = (u < HH) ? (bih[gt * HH + u] + bhh[gt * HH + u]) : 0.0f;
    }
}

__global__ __launch_bounds__(BLK, 1) void lstm_mfma(
    const float* __restrict__ seq,
    const float* __restrict__ Wih_e, const float* __restrict__ Whh_e,
    const float* __restrict__ bih_e, const float* __restrict__ bhh_e,
    const float* __restrict__ Wih_d, const float* __restrict__ Whh_d,
    const float* __restrict__ bih_d, const float* __restrict__ bhh_d,
    const float* __restrict__ Wl, const float* __restrict__ bl,
    float* __restrict__ out)
{
    // A frags (weights) hi/lo: 16 mt x 2 ks x 64 lanes = 2048 chunks x 16B = 32KB each
    __shared__ short8 Wh8[2048], Wl8[2048];
    // B frags (XH^T) hi/lo: 4 nt x 2 ks x 64 = 512 chunks = 8KB each
    __shared__ short8 Bh8[512], Bl8[512];
    __shared__ float bs[256];
    __shared__ float xstage[64 * 97];     // 16 steps x 6 feats per row, +1 pad
    __shared__ float Wls[NF * HH];
    __shared__ float bls[NF];

    unsigned short* WhU = (unsigned short*)Wh8;
    unsigned short* WlU = (unsigned short*)Wl8;
    unsigned short* BhU = (unsigned short*)Bh8;
    unsigned short* BlU = (unsigned short*)Bl8;

    const int tid  = threadIdx.x;
    const int w    = tid >> 6;        // wave id: owns M-tiles {2w, 2w+1}, all 4 N-tiles
    const int lane = tid & 63;
    const int q    = lane >> 4;       // k-block / C-row group
    const int l15  = lane & 15;       // C col = batch row within tile
    const int b0   = blockIdx.x * ROWS;

    // ---- init ----
    stage_weights(Wih_e, Whh_e, bih_e, bhh_e, WhU, WlU, bs, tid);
    for (int i = tid; i < NF * HH; i += BLK) Wls[i] = Wl[i];
    if (tid < NF) bls[tid] = bl[tid];
    for (int i = tid; i < 4096; i += BLK) { BhU[i] = 0; BlU[i] = 0; }  // h0=0 + K pad
    __syncthreads();

    float br[2][4];                                  // bias regs (i,f,g,o per m2)
    #pragma unroll
    for (int m2 = 0; m2 < 2; ++m2)
        #pragma unroll
        for (int r = 0; r < 4; ++r)
            br[m2][r] = bs[(2 * w + m2) * 16 + q * 4 + r];

    float c[2][4];
    #pragma unroll
    for (int m2 = 0; m2 < 2; ++m2)
        #pragma unroll
        for (int nt = 0; nt < 4; ++nt) c[m2][nt] = 0.0f;

    for (int t = 0; t < SS + TT; ++t) {
        const bool restage = (t == SS);
        const bool xchunk  = (t < SS) && ((t & 15) == 0);
        if (restage) stage_weights(Wih_d, Whh_d, bih_d, bhh_d, WhU, WlU, bs, tid);
        if (xchunk) {
            const int t0 = t;
            for (int idx = tid; idx < 64 * 96; idx += BLK) {
                int row = idx / 96, cc2 = idx - row * 96;
                float v = 0.0f;
                if (t0 + cc2 / 6 < SS)
                    v = seq[(size_t)(b0 + row) * SEQ_STRIDE + t0 * NF + cc2];
                xstage[row * 97 + cc2] = v;
            }
        }
        if (restage || xchunk) __syncthreads();
        if (restage) {
            #pragma unroll
            for (int m2 = 0; m2 < 2; ++m2)
                #pragma unroll
                for (int r = 0; r < 4; ++r)
                    br[m2][r] = bs[(2 * w + m2) * 16 + q * 4 + r];
        }

        // ---- phase W: write x_t (hi/lo) into B k-slots 0..5 ----
        if (t <= SS && tid < 384) {
            int row = tid & 63, n = tid >> 6;      // n is wave-uniform
            int px = (t < SS) ? t : (SS - 1);      // t==SS uses dec_in = x_{S-1}
            float x = xstage[row * 97 + (px & 15) * NF + n];
            unsigned short xh = f2bf(x);
            int pos = (row >> 4) * 1024 + (row & 15) * 8 + n;   // ks=0,kt=0,j=n
            BhU[pos] = xh; BlU[pos] = f2bf(x - bf2f(xh));
        }
        __syncthreads();   // barrier 1: x_t + h_{t-1} visible

        // ---- phase R: G^T = W @ XH^T via 3-term split MFMA ----
        short8 bf_h[4][2], bf_l[4][2];
        #pragma unroll
        for (int nt = 0; nt < 4; ++nt)
            #pragma unroll
            for (int ks = 0; ks < 2; ++ks) {
                bf_h[nt][ks] = Bh8[nt * 128 + ks * 64 + lane];
                bf_l[nt][ks] = Bl8[nt * 128 + ks * 64 + lane];
            }
        f32x4 acc[2][4];
        #pragma unroll
        for (int m2 = 0; m2 < 2; ++m2)
            #pragma unroll
            for (int nt = 0; nt < 4; ++nt)
                acc[m2][nt] = (f32x4){0.f, 0.f, 0.f, 0.f};
        #pragma unroll
        for (int m2 = 0; m2 < 2; ++m2)
            #pragma unroll
            for (int ks = 0; ks < 2; ++ks) {
                int ch = w * 256 + m2 * 128 + ks * 64 + lane;
                short8 ah = Wh8[ch];
                short8 al = Wl8[ch];
                #pragma unroll
                for (int nt = 0; nt < 4; ++nt) {
                    acc[m2][nt] = __builtin_amdgcn_mfma_f32_16x16x32_bf16(ah, bf_h[nt][ks], acc[m2][nt], 0, 0, 0);
                    acc[m2][nt] = __builtin_amdgcn_mfma_f32_16x16x32_bf16(ah, bf_l[nt][ks], acc[m2][nt], 0, 0, 0);
                    acc[m2][nt] = __builtin_amdgcn_mfma_f32_16x16x32_bf16(al, bf_h[nt][ks], acc[m2][nt], 0, 0, 0);
                }
            }
        __syncthreads();   // barrier 2: all B/A reads done before new writes

        // ---- phase U: lane-local cell update; scatter h_t back as B hi/lo ----
        #pragma unroll
        for (int m2 = 0; m2 < 2; ++m2) {
            const int u = (2 * w + m2) * 4 + q;    // unit this lane owns
            #pragma unroll
            for (int nt = 0; nt < 4; ++nt) {
                float gi = acc[m2][nt][0] + br[m2][0];
                float gf = acc[m2][nt][1] + br[m2][1];
                float gg = acc[m2][nt][2] + br[m2][2];
                float go = acc[m2][nt][3] + br[m2][3];
                float cc = sigm(gf) * c[m2][nt] + sigm(gi) * tanh_f(gg);
                c[m2][nt] = cc;
                float hh = sigm(go) * tanh_f(cc);
                if (u < HH) {
                    int k = NF + u;
                    int pos = (nt * 2 + (k >> 5)) * 512
                            + (((k >> 3) & 3) * 16 + l15) * 8 + (k & 7);
                    unsigned short hb = f2bf(hh);
                    BhU[pos] = hb; BlU[pos] = f2bf(hh - bf2f(hb));
                }
            }
        }

        // ---- decoder: pred = h @ Wl^T + bl; feed pred back as next x ----
        if (t >= SS) {
            __syncthreads();   // h_t visible
            if (tid < 384) {
                int row = tid & 63, n = tid >> 6;
                float a = bls[n];
                #pragma unroll
                for (int u2 = 0; u2 < HH; ++u2) {
                    int k = NF + u2;
                    int pos = ((row >> 4) * 2 + (k >> 5)) * 512
                            + (((k >> 3) & 3) * 16 + (row & 15)) * 8 + (k & 7);
                    float hv = bf2f(BhU[pos]) + bf2f(BlU[pos]);
                    a = fmaf(Wls[n * HH + u2], hv, a);
                }
                out[(size_t)(b0 + row) * (TT * NF) + (t - SS) * NF + n] = a;
                unsigned short ab = f2bf(a);
                int pos2 = (row >> 4) * 1024 + (row & 15) * 8 + n;
                BhU[pos2] = ab; BlU[pos2] = f2bf(a - bf2f(ab));
            }
        }
    }
}

extern "C" void kernel_launch(void* const* d_in, const int* in_sizes, int n_in,
                              void* d_out, int out_size, void* d_ws, size_t ws_size,
                              hipStream_t stream)
{
    const float* seq   = (const float*)d_in[0];
    const float* Wih_e = (const float*)d_in[1];
    const float* Whh_e = (const float*)d_in[2];
    const float* bih_e = (const float*)d_in[3];
    const float* bhh_e = (const float*)d_in[4];
    const float* Wih_d = (const float*)d_in[5];
    const float* Whh_d = (const float*)d_in[6];
    const float* bih_d = (const float*)d_in[7];
    const float* bhh_d = (const float*)d_in[8];
    const float* Wl    = (const float*)d_in[9];
    const float* bl    = (const float*)d_in[10];
    float* out = (float*)d_out;

    dim3 grid(BB / ROWS);   // 256 blocks -> 1 per CU
    dim3 block(BLK);        // 8 waves
    lstm_mfma<<<grid, block, 0, stream>>>(seq, Wih_e, Whh_e, bih_e, bhh_e,
                                          Wih_d, Whh_d, bih_d, bhh_d,
                                          Wl, bl, out);
}

// Round 3
// 648.667 us; speedup vs baseline: 2.7635x; 1.2451x over previous
//
#include <hip/hip_runtime.h>

#define BB 16384
#define SS 200
#define NF 6
#define HH 50
#define TT 5
#define ROWS 32
#define BLK 512
#define SEQ_STRIDE (SS * NF)   // 1200

typedef __attribute__((ext_vector_type(8))) short short8;
typedef __attribute__((ext_vector_type(4))) float f32x4;

__device__ __forceinline__ unsigned short f2bf_rne(float f) {
    unsigned u = __float_as_uint(f);
    u += 0x7FFF + ((u >> 16) & 1);
    return (unsigned short)(u >> 16);
}
// truncating split: hi = bits>>16, lo = v - hi  (|lo| <= 2^-8 |v|; 3-term MFMA
// covers hi*hi, hi*lo, lo*hi; dropped lo*lo ~ 2^-16 rel)
__device__ __forceinline__ unsigned short f2bf_t(float f) {
    return (unsigned short)(__float_as_uint(f) >> 16);
}
__device__ __forceinline__ float bf2f(unsigned short h) {
    return __uint_as_float(((unsigned)h) << 16);
}
__device__ __forceinline__ float sigm(float x)  { return 1.0f / (1.0f + __expf(-x)); }
__device__ __forceinline__ float tanh_f(float x){ return 2.0f / (1.0f + __expf(-2.0f*x)) - 1.0f; }

// Stage one bf16 half (hi or lo) of [Wih|Whh|pad] into A-fragment order.
// g2 = 4*u + gate (gate-interleaved); k = [x(0..5)|h(6..55)|pad]; frag chunk
// (mt,ks), lane kt*16+r, elem j  ->  ushort idx ((mt*2+ks)*64 + kt*16 + r)*8 + j
__device__ __forceinline__ void stage_half(const float* __restrict__ Wih,
                                           const float* __restrict__ Whh,
                                           int lo, unsigned short* dst, int tid)
{
    for (int idx = tid; idx < 256 * 64; idx += BLK) {
        int g2 = idx >> 6, k = idx & 63;
        int u = g2 >> 2, gt = g2 & 3;
        float v = 0.0f;
        if (u < HH) {
            int orow = gt * HH + u;
            if (k < NF)           v = Wih[orow * NF + k];
            else if (k < NF + HH) v = Whh[orow * HH + (k - NF)];
        }
        unsigned short hb = f2bf_rne(v);
        unsigned short res = lo ? f2bf_rne(v - bf2f(hb)) : hb;
        int mt = g2 >> 4, r = g2 & 15, ks = (k >> 5) & 1, kt = (k >> 3) & 3, j = k & 7;
        dst[((mt * 2 + ks) * 64 + kt * 16 + r) * 8 + j] = res;
    }
}

__device__ __forceinline__ void cell_upd(const f32x4& g, const float* br4, float& c,
                                         int u, int nt, int l15,
                                         unsigned short* BhU, unsigned short* BlU)
{
    float gi = g[0] + br4[0], gf = g[1] + br4[1];
    float gg = g[2] + br4[2], go = g[3] + br4[3];
    float cc = sigm(gf) * c + sigm(gi) * tanh_f(gg);
    c = cc;
    float hh = sigm(go) * tanh_f(cc);
    if (u < HH) {
        int k = NF + u;
        int pos = ((nt * 2 + (k >> 5)) * 64 + ((k >> 3) & 3) * 16 + l15) * 8 + (k & 7);
        unsigned short hb = f2bf_t(hh);
        BhU[pos] = hb;
        BlU[pos] = f2bf_t(hh - bf2f(hb));
    }
}

__global__ __launch_bounds__(BLK, 4) void lstm_mfma2(
    const float* __restrict__ seq,
    const float* __restrict__ Wih_e, const float* __restrict__ Whh_e,
    const float* __restrict__ bih_e, const float* __restrict__ bhh_e,
    const float* __restrict__ Wih_d, const float* __restrict__ Whh_d,
    const float* __restrict__ bih_d, const float* __restrict__ bhh_d,
    const float* __restrict__ Wl, const float* __restrict__ bl,
    float* __restrict__ out)
{
    __shared__ short8 Apool[2048];           // 32KB: weight staging, then xstage
    __shared__ short8 Bh8[256], Bl8[256];    // 4KB + 4KB  B frags (XH^T hi/lo)
    __shared__ float bs[256];
    __shared__ float Wls[NF * HH];
    __shared__ float bls[NF];

    unsigned short* ApoolU = (unsigned short*)Apool;
    float* xs = (float*)Apool;               // 32 x 97 floats (12.4KB) union
    unsigned short* BhU = (unsigned short*)Bh8;
    unsigned short* BlU = (unsigned short*)Bl8;

    const int tid  = threadIdx.x;
    const int w    = tid >> 6;
    const int lane = tid & 63;
    const int q    = lane >> 4;
    const int l15  = lane & 15;
    const int b0   = blockIdx.x * ROWS;
    const int mt0  = w;                      // M-tiles: {w, w+8}, tiles 13..15 dropped
    const int mt1  = w + 8;
    const bool has2 = (w < 5);               // mt1 <= 12

    // ---- one-time init ----
    for (int i = tid; i < 2048; i += BLK) { BhU[i] = 0; BlU[i] = 0; }   // h0=0 + pads
    for (int i = tid; i < NF * HH; i += BLK) Wls[i] = Wl[i];
    if (tid < NF) bls[tid] = bl[tid];
    for (int g2 = tid; g2 < 256; g2 += BLK) {
        int u = g2 >> 2, gt = g2 & 3;
        bs[g2] = (u < HH) ? (bih_e[gt * HH + u] + bhh_e[gt * HH + u]) : 0.0f;
    }

    short8 ah0[2], al0[2], ah1[2], al1[2];   // A frags in registers
    stage_half(Wih_e, Whh_e, 0, ApoolU, tid);
    __syncthreads();
    #pragma unroll
    for (int ks = 0; ks < 2; ++ks) {
        ah0[ks] = Apool[(mt0 * 2 + ks) * 64 + lane];
        if (has2) ah1[ks] = Apool[(mt1 * 2 + ks) * 64 + lane];
    }
    __syncthreads();
    stage_half(Wih_e, Whh_e, 1, ApoolU, tid);
    __syncthreads();
    #pragma unroll
    for (int ks = 0; ks < 2; ++ks) {
        al0[ks] = Apool[(mt0 * 2 + ks) * 64 + lane];
        if (has2) al1[ks] = Apool[(mt1 * 2 + ks) * 64 + lane];
    }
    __syncthreads();   // Apool now reusable as xstage

    float br[2][4];
    #pragma unroll
    for (int r = 0; r < 4; ++r) {
        br[0][r] = bs[mt0 * 16 + q * 4 + r];
        br[1][r] = bs[mt1 * 16 + q * 4 + r];
    }
    float c00 = 0.f, c01 = 0.f, c10 = 0.f, c11 = 0.f;

    for (int t = 0; t < SS + TT; ++t) {
        if (t == SS) {
            // ---- switch to decoder weights ----
            for (int g2 = tid; g2 < 256; g2 += BLK) {
                int u = g2 >> 2, gt = g2 & 3;
                bs[g2] = (u < HH) ? (bih_d[gt * HH + u] + bhh_d[gt * HH + u]) : 0.0f;
            }
            stage_half(Wih_d, Whh_d, 0, ApoolU, tid);
            __syncthreads();
            #pragma unroll
            for (int ks = 0; ks < 2; ++ks) {
                ah0[ks] = Apool[(mt0 * 2 + ks) * 64 + lane];
                if (has2) ah1[ks] = Apool[(mt1 * 2 + ks) * 64 + lane];
            }
            __syncthreads();
            stage_half(Wih_d, Whh_d, 1, ApoolU, tid);
            __syncthreads();
            #pragma unroll
            for (int ks = 0; ks < 2; ++ks) {
                al0[ks] = Apool[(mt0 * 2 + ks) * 64 + lane];
                if (has2) al1[ks] = Apool[(mt1 * 2 + ks) * 64 + lane];
            }
            #pragma unroll
            for (int r = 0; r < 4; ++r) {
                br[0][r] = bs[mt0 * 16 + q * 4 + r];
                br[1][r] = bs[mt1 * 16 + q * 4 + r];
            }
            // decoder input x_{S-1} already sits in the B x-slots from t=SS-1
        }
        if (t < SS && (t & 15) == 0) {
            // stage next 16 steps of x into xs (union w/ Apool; safe: t<SS)
            for (int idx = tid; idx < ROWS * 96; idx += BLK) {
                int row = idx / 96, cc2 = idx - row * 96;
                float v = 0.0f;
                if (t + cc2 / 6 < SS)
                    v = seq[(size_t)(b0 + row) * SEQ_STRIDE + t * NF + cc2];
                xs[row * 97 + cc2] = v;
            }
            __syncthreads();
        }

        // ---- phase W: write x_t hi/lo into B k-slots 0..5 ----
        if (t < SS && tid < 192) {
            int row = tid & 31, n = tid >> 5;
            float x = xs[row * 97 + (t & 15) * NF + n];
            unsigned short xh = f2bf_t(x);
            int pos = ((row >> 4) * 128 + (row & 15)) * 8 + n;   // ks=0,kt=0,j=n
            BhU[pos] = xh;
            BlU[pos] = f2bf_t(x - bf2f(xh));
        }
        __syncthreads();   // barrier 1: x_t + h_{t-1} visible

        // ---- phase R: G^T = W @ XH^T, A from registers, 3-term split ----
        f32x4 a00 = {0,0,0,0}, a01 = {0,0,0,0}, a10 = {0,0,0,0}, a11 = {0,0,0,0};
        #pragma unroll
        for (int ks = 0; ks < 2; ++ks) {
            short8 bh0 = Bh8[ks * 64 + lane];
            short8 bh1 = Bh8[(2 + ks) * 64 + lane];
            short8 bl0 = Bl8[ks * 64 + lane];
            short8 bl1 = Bl8[(2 + ks) * 64 + lane];
            a00 = __builtin_amdgcn_mfma_f32_16x16x32_bf16(ah0[ks], bh0, a00, 0, 0, 0);
            a00 = __builtin_amdgcn_mfma_f32_16x16x32_bf16(ah0[ks], bl0, a00, 0, 0, 0);
            a00 = __builtin_amdgcn_mfma_f32_16x16x32_bf16(al0[ks], bh0, a00, 0, 0, 0);
            a01 = __builtin_amdgcn_mfma_f32_16x16x32_bf16(ah0[ks], bh1, a01, 0, 0, 0);
            a01 = __builtin_amdgcn_mfma_f32_16x16x32_bf16(ah0[ks], bl1, a01, 0, 0, 0);
            a01 = __builtin_amdgcn_mfma_f32_16x16x32_bf16(al0[ks], bh1, a01, 0, 0, 0);
            if (has2) {
                a10 = __builtin_amdgcn_mfma_f32_16x16x32_bf16(ah1[ks], bh0, a10, 0, 0, 0);
                a10 = __builtin_amdgcn_mfma_f32_16x16x32_bf16(ah1[ks], bl0, a10, 0, 0, 0);
                a10 = __builtin_amdgcn_mfma_f32_16x16x32_bf16(al1[ks], bh0, a10, 0, 0, 0);
                a11 = __builtin_amdgcn_mfma_f32_16x16x32_bf16(ah1[ks], bh1, a11, 0, 0, 0);
                a11 = __builtin_amdgcn_mfma_f32_16x16x32_bf16(ah1[ks], bl1, a11, 0, 0, 0);
                a11 = __builtin_amdgcn_mfma_f32_16x16x32_bf16(al1[ks], bh1, a11, 0, 0, 0);
            }
        }
        __syncthreads();   // barrier 2: all B reads done before new writes

        // ---- phase U: lane-local cell update; scatter h_t hi/lo into B ----
        {
            const int u0 = mt0 * 4 + q;
            cell_upd(a00, br[0], c00, u0, 0, l15, BhU, BlU);
            cell_upd(a01, br[0], c01, u0, 1, l15, BhU, BlU);
            if (has2) {
                const int u1 = mt1 * 4 + q;
                cell_upd(a10, br[1], c10, u1, 0, l15, BhU, BlU);
                cell_upd(a11, br[1], c11, u1, 1, l15, BhU, BlU);
            }
        }

        // ---- decoder: pred = h @ Wl^T + bl; feed back as next x ----
        if (t >= SS) {
            __syncthreads();   // h_t visible
            if (tid < 192) {
                int row = tid & 31, n = tid >> 5;
                int ntb = row >> 4, lr = row & 15;
                float a = bls[n];
                #pragma unroll
                for (int u2 = 0; u2 < HH; ++u2) {
                    int k = NF + u2;
                    int pos = ((ntb * 2 + (k >> 5)) * 64 + ((k >> 3) & 3) * 16 + lr) * 8 + (k & 7);
                    float hv = bf2f(BhU[pos]) + bf2f(BlU[pos]);
                    a = fmaf(Wls[n * HH + u2], hv, a);
                }
                out[(size_t)(b0 + row) * (TT * NF) + (t - SS) * NF + n] = a;
                unsigned short ab = f2bf_t(a);
                int pos2 = (ntb * 128 + lr) * 8 + n;
                BhU[pos2] = ab;
                BlU[pos2] = f2bf_t(a - bf2f(ab));
            }
        }
    }
}

extern "C" void kernel_launch(void* const* d_in, const int* in_sizes, int n_in,
                              void* d_out, int out_size, void* d_ws, size_t ws_size,
                              hipStream_t stream)
{
    const float* seq   = (const float*)d_in[0];
    const float* Wih_e = (const float*)d_in[1];
    const float* Whh_e = (const float*)d_in[2];
    const float* bih_e = (const float*)d_in[3];
    const float* bhh_e = (const float*)d_in[4];
    const float* Wih_d = (const float*)d_in[5];
    const float* Whh_d = (const float*)d_in[6];
    const float* bih_d = (const float*)d_in[7];
    const float* bhh_d = (const float*)d_in[8];
    const float* Wl    = (const float*)d_in[9];
    const float* bl    = (const float*)d_in[10];
    float* out = (float*)d_out;

    dim3 grid(BB / ROWS);   // 512 blocks -> 2 per CU (LDS ~42KB, VGPR<=128)
    dim3 block(BLK);
    lstm_mfma2<<<grid, block, 0, stream>>>(seq, Wih_e, Whh_e, bih_e, bhh_e,
                                           Wih_d, Whh_d, bih_d, bhh_d,
                                           Wl, bl, out);
}

// Round 4
// 401.038 us; speedup vs baseline: 4.4699x; 1.6175x over previous
//
#include <hip/hip_runtime.h>

#define BB 16384
#define SS 200
#define NF 6
#define HH 50
#define TT 5
#define ROWS 32
#define BLK 512
#define SEQ_STRIDE (SS * NF)   // 1200

typedef __attribute__((ext_vector_type(8))) short short8;
typedef __attribute__((ext_vector_type(4))) float f32x4;

__device__ __forceinline__ unsigned short f2bf_rne(float f) {
    unsigned u = __float_as_uint(f);
    u += 0x7FFF + ((u >> 16) & 1);
    return (unsigned short)(u >> 16);
}
// truncating split: hi = bits>>16, lo = v - hi
__device__ __forceinline__ unsigned short f2bf_t(float f) {
    return (unsigned short)(__float_as_uint(f) >> 16);
}
__device__ __forceinline__ float bf2f(unsigned short h) {
    return __uint_as_float(((unsigned)h) << 16);
}
// Native-instruction activations: v_exp_f32 + v_rcp_f32 only (no IEEE divide).
#define LOG2E 1.44269504088896f
__device__ __forceinline__ float sigm(float x) {
    return __builtin_amdgcn_rcpf(1.0f + __builtin_amdgcn_exp2f(-LOG2E * x));
}
__device__ __forceinline__ float tanh_f(float x) {
    float r = __builtin_amdgcn_rcpf(1.0f + __builtin_amdgcn_exp2f(-2.0f * LOG2E * x));
    return fmaf(2.0f, r, -1.0f);
}

// Stage one bf16 half (hi or lo) of [Wih|Whh|pad] into A-fragment order.
__device__ __forceinline__ void stage_half(const float* __restrict__ Wih,
                                           const float* __restrict__ Whh,
                                           int lo, unsigned short* dst, int tid)
{
    for (int idx = tid; idx < 256 * 64; idx += BLK) {
        int g2 = idx >> 6, k = idx & 63;
        int u = g2 >> 2, gt = g2 & 3;
        float v = 0.0f;
        if (u < HH) {
            int orow = gt * HH + u;
            if (k < NF)           v = Wih[orow * NF + k];
            else if (k < NF + HH) v = Whh[orow * HH + (k - NF)];
        }
        unsigned short hb = f2bf_rne(v);
        unsigned short res = lo ? f2bf_rne(v - bf2f(hb)) : hb;
        int mt = g2 >> 4, r = g2 & 15, ks = (k >> 5) & 1, kt = (k >> 3) & 3, j = k & 7;
        dst[((mt * 2 + ks) * 64 + kt * 16 + r) * 8 + j] = res;
    }
}

__device__ __forceinline__ void cell_upd(const f32x4& g, const float* br4, float& c,
                                         int u, int nt, int l15,
                                         unsigned short* BhU, unsigned short* BlU)
{
    float gi = g[0] + br4[0], gf = g[1] + br4[1];
    float gg = g[2] + br4[2], go = g[3] + br4[3];
    float cc = sigm(gf) * c + sigm(gi) * tanh_f(gg);
    c = cc;
    float hh = sigm(go) * tanh_f(cc);
    if (u < HH) {
        int k = NF + u;
        int pos = ((nt * 2 + (k >> 5)) * 64 + ((k >> 3) & 3) * 16 + l15) * 8 + (k & 7);
        unsigned short hb = f2bf_t(hh);
        BhU[pos] = hb;
        BlU[pos] = f2bf_t(hh - bf2f(hb));
    }
}

__global__ __launch_bounds__(BLK, 4) void lstm_mfma3(
    const float* __restrict__ seq,
    const float* __restrict__ Wih_e, const float* __restrict__ Whh_e,
    const float* __restrict__ bih_e, const float* __restrict__ bhh_e,
    const float* __restrict__ Wih_d, const float* __restrict__ Whh_d,
    const float* __restrict__ bih_d, const float* __restrict__ bhh_d,
    const float* __restrict__ Wl, const float* __restrict__ bl,
    float* __restrict__ out)
{
    __shared__ short8 Apool[2048];           // 32KB: weight staging, then xstage
    __shared__ short8 Bh8[256], Bl8[256];    // 4KB + 4KB  B frags (XH^T hi/lo)
    __shared__ float bs[256];
    __shared__ float Wls[NF * HH];
    __shared__ float bls[NF];

    unsigned short* ApoolU = (unsigned short*)Apool;
    float* xs = (float*)Apool;               // 32 x 97 floats union
    unsigned short* BhU = (unsigned short*)Bh8;
    unsigned short* BlU = (unsigned short*)Bl8;

    const int tid  = threadIdx.x;
    const int w    = tid >> 6;
    const int lane = tid & 63;
    const int q    = lane >> 4;
    const int l15  = lane & 15;
    const int b0   = blockIdx.x * ROWS;
    const int mt0  = w;                      // M-tiles {w, w+8}; 13..15 dropped
    const int mt1  = w + 8;
    const bool has2 = (w < 5);

    // ---- one-time init ----
    for (int i = tid; i < 2048; i += BLK) { BhU[i] = 0; BlU[i] = 0; }
    for (int i = tid; i < NF * HH; i += BLK) Wls[i] = Wl[i];
    if (tid < NF) bls[tid] = bl[tid];
    for (int g2 = tid; g2 < 256; g2 += BLK) {
        int u = g2 >> 2, gt = g2 & 3;
        bs[g2] = (u < HH) ? (bih_e[gt * HH + u] + bhh_e[gt * HH + u]) : 0.0f;
    }

    short8 ah0[2], al0[2], ah1[2], al1[2];
    stage_half(Wih_e, Whh_e, 0, ApoolU, tid);
    __syncthreads();
    #pragma unroll
    for (int ks = 0; ks < 2; ++ks) {
        ah0[ks] = Apool[(mt0 * 2 + ks) * 64 + lane];
        if (has2) ah1[ks] = Apool[(mt1 * 2 + ks) * 64 + lane];
    }
    __syncthreads();
    stage_half(Wih_e, Whh_e, 1, ApoolU, tid);
    __syncthreads();
    #pragma unroll
    for (int ks = 0; ks < 2; ++ks) {
        al0[ks] = Apool[(mt0 * 2 + ks) * 64 + lane];
        if (has2) al1[ks] = Apool[(mt1 * 2 + ks) * 64 + lane];
    }
    __syncthreads();

    float br[2][4];
    #pragma unroll
    for (int r = 0; r < 4; ++r) {
        br[0][r] = bs[mt0 * 16 + q * 4 + r];
        br[1][r] = bs[mt1 * 16 + q * 4 + r];
    }
    float c00 = 0.f, c01 = 0.f, c10 = 0.f, c11 = 0.f;

    for (int t = 0; t < SS + TT; ++t) {
        if (t == SS) {
            for (int g2 = tid; g2 < 256; g2 += BLK) {
                int u = g2 >> 2, gt = g2 & 3;
                bs[g2] = (u < HH) ? (bih_d[gt * HH + u] + bhh_d[gt * HH + u]) : 0.0f;
            }
            stage_half(Wih_d, Whh_d, 0, ApoolU, tid);
            __syncthreads();
            #pragma unroll
            for (int ks = 0; ks < 2; ++ks) {
                ah0[ks] = Apool[(mt0 * 2 + ks) * 64 + lane];
                if (has2) ah1[ks] = Apool[(mt1 * 2 + ks) * 64 + lane];
            }
            __syncthreads();
            stage_half(Wih_d, Whh_d, 1, ApoolU, tid);
            __syncthreads();
            #pragma unroll
            for (int ks = 0; ks < 2; ++ks) {
                al0[ks] = Apool[(mt0 * 2 + ks) * 64 + lane];
                if (has2) al1[ks] = Apool[(mt1 * 2 + ks) * 64 + lane];
            }
            #pragma unroll
            for (int r = 0; r < 4; ++r) {
                br[0][r] = bs[mt0 * 16 + q * 4 + r];
                br[1][r] = bs[mt1 * 16 + q * 4 + r];
            }
        }
        if (t < SS && (t & 15) == 0) {
            for (int idx = tid; idx < ROWS * 96; idx += BLK) {
                int row = idx / 96, cc2 = idx - row * 96;
                float v = 0.0f;
                if (t + cc2 / 6 < SS)
                    v = seq[(size_t)(b0 + row) * SEQ_STRIDE + t * NF + cc2];
                xs[row * 97 + cc2] = v;
            }
            __syncthreads();
        }

        // ---- phase W: write x_t hi/lo into B k-slots 0..5 ----
        if (t < SS && tid < 192) {
            int row = tid & 31, n = tid >> 5;
            float x = xs[row * 97 + (t & 15) * NF + n];
            unsigned short xh = f2bf_t(x);
            int pos = ((row >> 4) * 128 + (row & 15)) * 8 + n;
            BhU[pos] = xh;
            BlU[pos] = f2bf_t(x - bf2f(xh));
        }
        __syncthreads();   // barrier 1: x_t + h_{t-1} visible

        // ---- phase R: MFMA, A in registers, 3-term split ----
        f32x4 a00 = {0,0,0,0}, a01 = {0,0,0,0}, a10 = {0,0,0,0}, a11 = {0,0,0,0};
        #pragma unroll
        for (int ks = 0; ks < 2; ++ks) {
            short8 bh0 = Bh8[ks * 64 + lane];
            short8 bh1 = Bh8[(2 + ks) * 64 + lane];
            short8 bl0 = Bl8[ks * 64 + lane];
            short8 bl1 = Bl8[(2 + ks) * 64 + lane];
            a00 = __builtin_amdgcn_mfma_f32_16x16x32_bf16(ah0[ks], bh0, a00, 0, 0, 0);
            a00 = __builtin_amdgcn_mfma_f32_16x16x32_bf16(ah0[ks], bl0, a00, 0, 0, 0);
            a00 = __builtin_amdgcn_mfma_f32_16x16x32_bf16(al0[ks], bh0, a00, 0, 0, 0);
            a01 = __builtin_amdgcn_mfma_f32_16x16x32_bf16(ah0[ks], bh1, a01, 0, 0, 0);
            a01 = __builtin_amdgcn_mfma_f32_16x16x32_bf16(ah0[ks], bl1, a01, 0, 0, 0);
            a01 = __builtin_amdgcn_mfma_f32_16x16x32_bf16(al0[ks], bh1, a01, 0, 0, 0);
            if (has2) {
                a10 = __builtin_amdgcn_mfma_f32_16x16x32_bf16(ah1[ks], bh0, a10, 0, 0, 0);
                a10 = __builtin_amdgcn_mfma_f32_16x16x32_bf16(ah1[ks], bl0, a10, 0, 0, 0);
                a10 = __builtin_amdgcn_mfma_f32_16x16x32_bf16(al1[ks], bh0, a10, 0, 0, 0);
                a11 = __builtin_amdgcn_mfma_f32_16x16x32_bf16(ah1[ks], bh1, a11, 0, 0, 0);
                a11 = __builtin_amdgcn_mfma_f32_16x16x32_bf16(ah1[ks], bl1, a11, 0, 0, 0);
                a11 = __builtin_amdgcn_mfma_f32_16x16x32_bf16(al1[ks], bh1, a11, 0, 0, 0);
            }
        }
        __syncthreads();   // barrier 2: B reads done before new writes

        // ---- phase U: lane-local cell update; scatter h_t into B ----
        {
            const int u0 = mt0 * 4 + q;
            cell_upd(a00, br[0], c00, u0, 0, l15, BhU, BlU);
            cell_upd(a01, br[0], c01, u0, 1, l15, BhU, BlU);
            if (has2) {
                const int u1 = mt1 * 4 + q;
                cell_upd(a10, br[1], c10, u1, 0, l15, BhU, BlU);
                cell_upd(a11, br[1], c11, u1, 1, l15, BhU, BlU);
            }
        }

        // ---- decoder ----
        if (t >= SS) {
            __syncthreads();
            if (tid < 192) {
                int row = tid & 31, n = tid >> 5;
                int ntb = row >> 4, lr = row & 15;
                float a = bls[n];
                #pragma unroll
                for (int u2 = 0; u2 < HH; ++u2) {
                    int k = NF + u2;
                    int pos = ((ntb * 2 + (k >> 5)) * 64 + ((k >> 3) & 3) * 16 + lr) * 8 + (k & 7);
                    float hv = bf2f(BhU[pos]) + bf2f(BlU[pos]);
                    a = fmaf(Wls[n * HH + u2], hv, a);
                }
                out[(size_t)(b0 + row) * (TT * NF) + (t - SS) * NF + n] = a;
                unsigned short ab = f2bf_t(a);
                int pos2 = (ntb * 128 + lr) * 8 + n;
                BhU[pos2] = ab;
                BlU[pos2] = f2bf_t(a - bf2f(ab));
            }
        }
    }
}

extern "C" void kernel_launch(void* const* d_in, const int* in_sizes, int n_in,
                              void* d_out, int out_size, void* d_ws, size_t ws_size,
                              hipStream_t stream)
{
    const float* seq   = (const float*)d_in[0];
    const float* Wih_e = (const float*)d_in[1];
    const float* Whh_e = (const float*)d_in[2];
    const float* bih_e = (const float*)d_in[3];
    const float* bhh_e = (const float*)d_in[4];
    const float* Wih_d = (const float*)d_in[5];
    const float* Whh_d = (const float*)d_in[6];
    const float* bih_d = (const float*)d_in[7];
    const float* bhh_d = (const float*)d_in[8];
    const float* Wl    = (const float*)d_in[9];
    const float* bl    = (const float*)d_in[10];
    float* out = (float*)d_out;

    dim3 grid(BB / ROWS);   // 512 blocks -> 2 per CU
    dim3 block(BLK);
    lstm_mfma3<<<grid, block, 0, stream>>>(seq, Wih_e, Whh_e, bih_e, bhh_e,
                                           Wih_d, Whh_d, bih_d, bhh_d,
                                           Wl, bl, out);
}

// Round 6
// 397.795 us; speedup vs baseline: 4.5063x; 1.0082x over previous
//
#include <hip/hip_runtime.h>

#define BB 16384
#define SS 200
#define NF 6
#define HH 50
#define TT 5
#define ROWS 16
#define BLK 512
#define SEQ_STRIDE (SS * NF)   // 1200

typedef __attribute__((ext_vector_type(8))) short short8;
typedef __attribute__((ext_vector_type(4))) float f32x4;

__device__ __forceinline__ unsigned short f2bf_rne(float f) {
    unsigned u = __float_as_uint(f);
    u += 0x7FFF + ((u >> 16) & 1);
    return (unsigned short)(u >> 16);
}
__device__ __forceinline__ unsigned short f2bf_t(float f) {
    return (unsigned short)(__float_as_uint(f) >> 16);
}
__device__ __forceinline__ float bf2f(unsigned short h) {
    return __uint_as_float(((unsigned)h) << 16);
}
#define LOG2E 1.44269504088896f
__device__ __forceinline__ float sigm(float x) {
    return __builtin_amdgcn_rcpf(1.0f + __builtin_amdgcn_exp2f(-LOG2E * x));
}
__device__ __forceinline__ float tanh_f(float x) {
    float r = __builtin_amdgcn_rcpf(1.0f + __builtin_amdgcn_exp2f(-2.0f * LOG2E * x));
    return fmaf(2.0f, r, -1.0f);
}

// Gather one M-tile's A fragments (hi+lo split) straight from global.
// Lane kt*16+r holds A[mt*16+r][ks*32+kt*8+j], j=0..7.
__device__ __forceinline__ void load_a(const float* __restrict__ Wih,
                                       const float* __restrict__ Whh,
                                       int mt, int lane, short8* ah, short8* al)
{
    const int r = lane & 15, kt = lane >> 4;
    const int g2 = mt * 16 + r, u = g2 >> 2, gt = g2 & 3;
    const bool valid = (u < HH);
    const int orow = gt * HH + u;
    #pragma unroll
    for (int ks = 0; ks < 2; ++ks) {
        short8 h8, l8;
        #pragma unroll
        for (int j = 0; j < 8; ++j) {
            int k = ks * 32 + kt * 8 + j;
            float v = 0.0f;
            if (valid && k < NF + HH)
                v = (k < NF) ? Wih[orow * NF + k] : Whh[orow * HH + (k - NF)];
            unsigned short hb = f2bf_rne(v);
            h8[j] = (short)hb;
            l8[j] = (short)f2bf_rne(v - bf2f(hb));
        }
        ah[ks] = h8;
        al[ks] = l8;
    }
}

__device__ __forceinline__ void cell_upd(const f32x4& g, float& c, int u, int l15,
                                         unsigned short* BhQ, unsigned short* BlQ)
{
    float cc = sigm(g[1]) * c + sigm(g[0]) * tanh_f(g[2]);
    c = cc;
    float hh = sigm(g[3]) * tanh_f(cc);
    if (u < HH) {
        int k = NF + u;
        int pos = (((k >> 5) * 64) + ((k >> 3) & 3) * 16 + l15) * 8 + (k & 7);
        unsigned short hb = f2bf_t(hh);
        BhQ[pos] = hb;
        BlQ[pos] = f2bf_t(hh - bf2f(hb));
    }
}

__global__ __launch_bounds__(BLK, 8) void lstm_mfma4(
    const float* __restrict__ seq,
    const float* __restrict__ Wih_e, const float* __restrict__ Whh_e,
    const float* __restrict__ bih_e, const float* __restrict__ bhh_e,
    const float* __restrict__ Wih_d, const float* __restrict__ Whh_d,
    const float* __restrict__ bih_d, const float* __restrict__ bhh_d,
    const float* __restrict__ Wl, const float* __restrict__ bl,
    float* __restrict__ out)
{
    __shared__ short8 Bh8[256], Bl8[256];   // 2 buffers x 128 chunks (4KB+4KB)
    __shared__ float bs[256];               // fused bias in g2 order
    __shared__ float xs[ROWS * 97];         // 16 steps x 6 feats per row
    __shared__ float Wls[NF * HH];
    __shared__ float bls[NF];

    unsigned short* BhU = (unsigned short*)Bh8;   // buffer P at ushort ofs P*1024
    unsigned short* BlU = (unsigned short*)Bl8;

    const int tid  = threadIdx.x;
    const int w    = tid >> 6;
    const int lane = tid & 63;
    const int q    = lane >> 4;
    const int l15  = lane & 15;
    const int b0   = blockIdx.x * ROWS;
    const int mt0  = w, mt1 = w + 8;        // 13 M-tiles: {0..7} + {8..12}
    const bool has2 = (w < 5);

    // ---- one-time init ----
    {
        unsigned* zh = (unsigned*)Bh8;
        unsigned* zl = (unsigned*)Bl8;
        for (int i = tid; i < 1024; i += BLK) { zh[i] = 0u; zl[i] = 0u; }
    }
    for (int i = tid; i < NF * HH; i += BLK) Wls[i] = Wl[i];
    if (tid < NF) bls[tid] = bl[tid];
    for (int g2 = tid; g2 < 256; g2 += BLK) {
        int u = g2 >> 2, gt = g2 & 3;
        bs[g2] = (u < HH) ? (bih_e[gt * HH + u] + bhh_e[gt * HH + u]) : 0.0f;
    }

    short8 ah0[2], al0[2], ah1[2], al1[2];
    load_a(Wih_e, Whh_e, mt0, lane, ah0, al0);
    if (has2) load_a(Wih_e, Whh_e, mt1, lane, ah1, al1);

    // xstage chunk for steps 0..15
    for (int idx = tid; idx < ROWS * 96; idx += BLK) {
        int row = idx / 96, cc = idx - row * 96;
        xs[row * 97 + cc] = seq[(size_t)(b0 + row) * SEQ_STRIDE + cc];
    }
    __syncthreads();

    // prologue: x_0 into buf0 (h-slots already zero = h0)
    if (tid < 96) {
        int row = tid & 15, n = tid >> 4;
        float x = xs[row * 97 + n];
        unsigned short xh = f2bf_rne(x);
        BhU[row * 8 + n] = xh;
        BlU[row * 8 + n] = f2bf_rne(x - bf2f(xh));
    }
    __syncthreads();

    float c0 = 0.0f, c1 = 0.0f;

    for (int t = 0; t < SS + TT; ++t) {
        const int P = t & 1, Q = P ^ 1;
        const int Pofs8 = P * 128;          // short8 offset of read buffer
        unsigned short* BhQ = BhU + Q * 1024;
        unsigned short* BlQ = BlU + Q * 1024;

        if (t == SS) {
            // switch to decoder weights; prior reads fenced by end barrier of SS-1
            load_a(Wih_d, Whh_d, mt0, lane, ah0, al0);
            if (has2) load_a(Wih_d, Whh_d, mt1, lane, ah1, al1);
            for (int g2 = tid; g2 < 256; g2 += BLK) {
                int u = g2 >> 2, gt = g2 & 3;
                bs[g2] = (u < HH) ? (bih_d[gt * HH + u] + bhh_d[gt * HH + u]) : 0.0f;
            }
            __syncthreads();
        }
        if ((t & 15) == 15 && t < SS - 1) {
            // refresh xs for steps t+1 .. t+16 (prev reads done at end barrier)
            const int t0 = t + 1;
            for (int idx = tid; idx < ROWS * 96; idx += BLK) {
                int row = idx / 96, cc = idx - row * 96;
                float v = 0.0f;
                if (t0 + cc / 6 < SS)
                    v = seq[(size_t)(b0 + row) * SEQ_STRIDE + t0 * NF + cc];
                xs[row * 97 + cc] = v;
            }
            __syncthreads();
        }

        // ---- MFMA: acc starts at bias (broadcast ds_read_b128) ----
        f32x4 acc0 = *(const f32x4*)&bs[mt0 * 16 + q * 4];
        f32x4 acc1 = has2 ? *(const f32x4*)&bs[mt1 * 16 + q * 4]
                          : (f32x4){0.f, 0.f, 0.f, 0.f};
        #pragma unroll
        for (int ks = 0; ks < 2; ++ks) {
            short8 bh = Bh8[Pofs8 + ks * 64 + lane];
            short8 bv = Bl8[Pofs8 + ks * 64 + lane];
            acc0 = __builtin_amdgcn_mfma_f32_16x16x32_bf16(ah0[ks], bh, acc0, 0, 0, 0);
            acc0 = __builtin_amdgcn_mfma_f32_16x16x32_bf16(ah0[ks], bv, acc0, 0, 0, 0);
            acc0 = __builtin_amdgcn_mfma_f32_16x16x32_bf16(al0[ks], bh, acc0, 0, 0, 0);
            if (has2) {
                acc1 = __builtin_amdgcn_mfma_f32_16x16x32_bf16(ah1[ks], bh, acc1, 0, 0, 0);
                acc1 = __builtin_amdgcn_mfma_f32_16x16x32_bf16(ah1[ks], bv, acc1, 0, 0, 0);
                acc1 = __builtin_amdgcn_mfma_f32_16x16x32_bf16(al1[ks], bh, acc1, 0, 0, 0);
            }
        }

        // ---- write x_{t+1} into Q (encoder source; t==SS-1 writes dec_in) ----
        if (t < SS && tid < 96) {
            int row = tid & 15, n = tid >> 4;
            int px = (t + 1 < SS) ? t + 1 : SS - 1;
            float x = xs[row * 97 + (px & 15) * NF + n];
            unsigned short xh = f2bf_rne(x);
            BhQ[row * 8 + n] = xh;
            BlQ[row * 8 + n] = f2bf_rne(x - bf2f(xh));
        }

        // ---- lane-local cell update; h_t into Q ----
        cell_upd(acc0, c0, mt0 * 4 + q, l15, BhQ, BlQ);
        if (has2) cell_upd(acc1, c1, mt1 * 4 + q, l15, BhQ, BlQ);

        // ---- decoder: pred from h_t (needs barrier), feed back as x_{t+1} ----
        if (t >= SS) {
            __syncthreads();   // h_t visible in Q
            if (tid < 96) {
                int row = tid & 15, n = tid >> 4;
                float a = bls[n];
                #pragma unroll
                for (int u2 = 0; u2 < HH; ++u2) {
                    int k = NF + u2;
                    int pos = ((k >> 5) * 64 + ((k >> 3) & 3) * 16 + row) * 8 + (k & 7);
                    float hv = bf2f(BhQ[pos]) + bf2f(BlQ[pos]);
                    a = fmaf(Wls[n * HH + u2], hv, a);
                }
                out[(size_t)(b0 + row) * (TT * NF) + (t - SS) * NF + n] = a;
                unsigned short ab = f2bf_rne(a);
                BhQ[row * 8 + n] = ab;
                BlQ[row * 8 + n] = f2bf_rne(a - bf2f(ab));
            }
        }

        __syncthreads();       // Q complete; P free for reuse next step
    }
}

extern "C" void kernel_launch(void* const* d_in, const int* in_sizes, int n_in,
                              void* d_out, int out_size, void* d_ws, size_t ws_size,
                              hipStream_t stream)
{
    const float* seq   = (const float*)d_in[0];
    const float* Wih_e = (const float*)d_in[1];
    const float* Whh_e = (const float*)d_in[2];
    const float* bih_e = (const float*)d_in[3];
    const float* bhh_e = (const float*)d_in[4];
    const float* Wih_d = (const float*)d_in[5];
    const float* Whh_d = (const float*)d_in[6];
    const float* bih_d = (const float*)d_in[7];
    const float* bhh_d = (const float*)d_in[8];
    const float* Wl    = (const float*)d_in[9];
    const float* bl    = (const float*)d_in[10];
    float* out = (float*)d_out;

    dim3 grid(BB / ROWS);   // 1024 blocks -> 4 per CU -> 8 waves/SIMD
    dim3 block(BLK);
    lstm_mfma4<<<grid, block, 0, stream>>>(seq, Wih_e, Whh_e, bih_e, bhh_e,
                                           Wih_d, Whh_d, bih_d, bhh_d,
                                           Wl, bl, out);
}

// Round 7
// 394.786 us; speedup vs baseline: 4.5407x; 1.0076x over previous
//
#include <hip/hip_runtime.h>

#define BB 16384
#define SS 200
#define NF 6
#define HH 50
#define TT 5
#define ROWS 16
#define BLK 512
#define SEQ_STRIDE (SS * NF)   // 1200

typedef __attribute__((ext_vector_type(8))) short short8;
typedef __attribute__((ext_vector_type(4))) float f32x4;

__device__ __forceinline__ unsigned short f2bf_rne(float f) {
    unsigned u = __float_as_uint(f);
    u += 0x7FFF + ((u >> 16) & 1);
    return (unsigned short)(u >> 16);
}
__device__ __forceinline__ unsigned short f2bf_t(float f) {
    return (unsigned short)(__float_as_uint(f) >> 16);
}
__device__ __forceinline__ float bf2f(unsigned short h) {
    return __uint_as_float(((unsigned)h) << 16);
}
#define LOG2E 1.44269504088896f
__device__ __forceinline__ float sigm(float x) {
    return __builtin_amdgcn_rcpf(1.0f + __builtin_amdgcn_exp2f(-LOG2E * x));
}
__device__ __forceinline__ float tanh_f(float x) {
    float r = __builtin_amdgcn_rcpf(1.0f + __builtin_amdgcn_exp2f(-2.0f * LOG2E * x));
    return fmaf(2.0f, r, -1.0f);
}

// Gather one M-tile's A fragments (hi+lo split) straight from global.
// Lane kt*16+r holds A[mt*16+r][ks*32+kt*8+j], j=0..7.
__device__ __forceinline__ void load_a(const float* __restrict__ Wih,
                                       const float* __restrict__ Whh,
                                       int mt, int lane, short8* ah, short8* al)
{
    const int r = lane & 15, kt = lane >> 4;
    const int g2 = mt * 16 + r, u = g2 >> 2, gt = g2 & 3;
    const bool valid = (u < HH);
    const int orow = gt * HH + u;
    #pragma unroll
    for (int ks = 0; ks < 2; ++ks) {
        short8 h8, l8;
        #pragma unroll
        for (int j = 0; j < 8; ++j) {
            int k = ks * 32 + kt * 8 + j;
            float v = 0.0f;
            if (valid && k < NF + HH)
                v = (k < NF) ? Wih[orow * NF + k] : Whh[orow * HH + (k - NF)];
            unsigned short hb = f2bf_rne(v);
            h8[j] = (short)hb;
            l8[j] = (short)f2bf_rne(v - bf2f(hb));
        }
        ah[ks] = h8;
        al[ks] = l8;
    }
}

__device__ __forceinline__ void cell_upd(const f32x4& g, float& c, int u, int l15,
                                         unsigned short* BhQ, unsigned short* BlQ)
{
    float cc = sigm(g[1]) * c + sigm(g[0]) * tanh_f(g[2]);
    c = cc;
    float hh = sigm(g[3]) * tanh_f(cc);
    if (u < HH) {
        int k = NF + u;
        int pos = (((k >> 5) * 64) + ((k >> 3) & 3) * 16 + l15) * 8 + (k & 7);
        unsigned short hb = f2bf_t(hh);
        BhQ[pos] = hb;
        BlQ[pos] = f2bf_t(hh - bf2f(hb));
    }
}

__global__ __launch_bounds__(BLK, 6) void lstm_mfma5(
    const float* __restrict__ seq,
    const float* __restrict__ Wih_e, const float* __restrict__ Whh_e,
    const float* __restrict__ bih_e, const float* __restrict__ bhh_e,
    const float* __restrict__ Wih_d, const float* __restrict__ Whh_d,
    const float* __restrict__ bih_d, const float* __restrict__ bhh_d,
    const float* __restrict__ Wl, const float* __restrict__ bl,
    float* __restrict__ out)
{
    __shared__ short8 Bh8[256], Bl8[256];   // 2 buffers x 128 chunks (4KB+4KB)
    __shared__ float bs[256];               // fused bias in g2 order
    __shared__ float xs[ROWS * 97];         // 16 steps x 6 feats per row
    __shared__ float Wls[NF * HH];
    __shared__ float bls[NF];

    unsigned short* BhU = (unsigned short*)Bh8;   // buffer P at ushort ofs P*1024
    unsigned short* BlU = (unsigned short*)Bl8;

    const int tid  = threadIdx.x;
    const int w    = tid >> 6;
    const int lane = tid & 63;
    const int q    = lane >> 4;
    const int l15  = lane & 15;
    const int b0   = blockIdx.x * ROWS;
    const int mt0  = w, mt1 = w + 8;        // 13 M-tiles: {0..7} + {8..12}
    const bool has2 = (w < 5);

    // ---- one-time init ----
    {
        unsigned* zh = (unsigned*)Bh8;
        unsigned* zl = (unsigned*)Bl8;
        for (int i = tid; i < 1024; i += BLK) { zh[i] = 0u; zl[i] = 0u; }
    }
    for (int i = tid; i < NF * HH; i += BLK) Wls[i] = Wl[i];
    if (tid < NF) bls[tid] = bl[tid];
    for (int g2 = tid; g2 < 256; g2 += BLK) {
        int u = g2 >> 2, gt = g2 & 3;
        bs[g2] = (u < HH) ? (bih_e[gt * HH + u] + bhh_e[gt * HH + u]) : 0.0f;
    }

    short8 ah0[2], al0[2], ah1[2], al1[2];
    load_a(Wih_e, Whh_e, mt0, lane, ah0, al0);
    if (has2) load_a(Wih_e, Whh_e, mt1, lane, ah1, al1);

    // xstage chunk for steps 0..15
    for (int idx = tid; idx < ROWS * 96; idx += BLK) {
        int row = idx / 96, cc = idx - row * 96;
        xs[row * 97 + cc] = seq[(size_t)(b0 + row) * SEQ_STRIDE + cc];
    }
    __syncthreads();

    // prologue: x_0 into buf0 (h-slots already zero = h0)
    if (tid < 96) {
        int row = tid & 15, n = tid >> 4;
        float x = xs[row * 97 + n];
        unsigned short xh = f2bf_rne(x);
        BhU[row * 8 + n] = xh;
        BlU[row * 8 + n] = f2bf_rne(x - bf2f(xh));
    }
    __syncthreads();

    float c0 = 0.0f, c1 = 0.0f;

    for (int t = 0; t < SS + TT; ++t) {
        const int P = t & 1, Q = P ^ 1;
        const int Pofs8 = P * 128;          // short8 offset of read buffer
        unsigned short* BhQ = BhU + Q * 1024;
        unsigned short* BlQ = BlU + Q * 1024;

        if (t == SS) {
            // switch to decoder weights; prior reads fenced by end barrier of SS-1
            load_a(Wih_d, Whh_d, mt0, lane, ah0, al0);
            if (has2) load_a(Wih_d, Whh_d, mt1, lane, ah1, al1);
            for (int g2 = tid; g2 < 256; g2 += BLK) {
                int u = g2 >> 2, gt = g2 & 3;
                bs[g2] = (u < HH) ? (bih_d[gt * HH + u] + bhh_d[gt * HH + u]) : 0.0f;
            }
            __syncthreads();
        }
        if ((t & 15) == 15 && t < SS - 1) {
            // refresh xs for steps t+1 .. t+16 (prev reads done at end barrier)
            const int t0 = t + 1;
            for (int idx = tid; idx < ROWS * 96; idx += BLK) {
                int row = idx / 96, cc = idx - row * 96;
                float v = 0.0f;
                if (t0 + cc / 6 < SS)
                    v = seq[(size_t)(b0 + row) * SEQ_STRIDE + t0 * NF + cc];
                xs[row * 97 + cc] = v;
            }
            __syncthreads();
        }

        // ---- MFMA: acc starts at bias (broadcast ds_read_b128) ----
        f32x4 acc0 = *(const f32x4*)&bs[mt0 * 16 + q * 4];
        f32x4 acc1 = has2 ? *(const f32x4*)&bs[mt1 * 16 + q * 4]
                          : (f32x4){0.f, 0.f, 0.f, 0.f};
        #pragma unroll
        for (int ks = 0; ks < 2; ++ks) {
            short8 bh = Bh8[Pofs8 + ks * 64 + lane];
            short8 bv = Bl8[Pofs8 + ks * 64 + lane];
            acc0 = __builtin_amdgcn_mfma_f32_16x16x32_bf16(ah0[ks], bh, acc0, 0, 0, 0);
            acc0 = __builtin_amdgcn_mfma_f32_16x16x32_bf16(ah0[ks], bv, acc0, 0, 0, 0);
            acc0 = __builtin_amdgcn_mfma_f32_16x16x32_bf16(al0[ks], bh, acc0, 0, 0, 0);
            if (has2) {
                acc1 = __builtin_amdgcn_mfma_f32_16x16x32_bf16(ah1[ks], bh, acc1, 0, 0, 0);
                acc1 = __builtin_amdgcn_mfma_f32_16x16x32_bf16(ah1[ks], bv, acc1, 0, 0, 0);
                acc1 = __builtin_amdgcn_mfma_f32_16x16x32_bf16(al1[ks], bh, acc1, 0, 0, 0);
            }
        }

        // ---- write x_{t+1} into Q (encoder source; t==SS-1 writes dec_in) ----
        if (t < SS && tid < 96) {
            int row = tid & 15, n = tid >> 4;
            int px = (t + 1 < SS) ? t + 1 : SS - 1;
            float x = xs[row * 97 + (px & 15) * NF + n];
            unsigned short xh = f2bf_rne(x);
            BhQ[row * 8 + n] = xh;
            BlQ[row * 8 + n] = f2bf_rne(x - bf2f(xh));
        }

        // ---- lane-local cell update; h_t into Q ----
        cell_upd(acc0, c0, mt0 * 4 + q, l15, BhQ, BlQ);
        if (has2) cell_upd(acc1, c1, mt1 * 4 + q, l15, BhQ, BlQ);

        // ---- decoder: pred from h_t (needs barrier), feed back as x_{t+1} ----
        if (t >= SS) {
            __syncthreads();   // h_t visible in Q
            if (tid < 96) {
                int row = tid & 15, n = tid >> 4;
                float a = bls[n];
                #pragma unroll
                for (int u2 = 0; u2 < HH; ++u2) {
                    int k = NF + u2;
                    int pos = ((k >> 5) * 64 + ((k >> 3) & 3) * 16 + row) * 8 + (k & 7);
                    float hv = bf2f(BhQ[pos]) + bf2f(BlQ[pos]);
                    a = fmaf(Wls[n * HH + u2], hv, a);
                }
                out[(size_t)(b0 + row) * (TT * NF) + (t - SS) * NF + n] = a;
                unsigned short ab = f2bf_rne(a);
                BhQ[row * 8 + n] = ab;
                BlQ[row * 8 + n] = f2bf_rne(a - bf2f(ab));
            }
        }

        __syncthreads();       // Q complete; P free for reuse next step
    }
}

extern "C" void kernel_launch(void* const* d_in, const int* in_sizes, int n_in,
                              void* d_out, int out_size, void* d_ws, size_t ws_size,
                              hipStream_t stream)
{
    const float* seq   = (const float*)d_in[0];
    const float* Wih_e = (const float*)d_in[1];
    const float* Whh_e = (const float*)d_in[2];
    const float* bih_e = (const float*)d_in[3];
    const float* bhh_e = (const float*)d_in[4];
    const float* Wih_d = (const float*)d_in[5];
    const float* Whh_d = (const float*)d_in[6];
    const float* bih_d = (const float*)d_in[7];
    const float* bhh_d = (const float*)d_in[8];
    const float* Wl    = (const float*)d_in[9];
    const float* bl    = (const float*)d_in[10];
    float* out = (float*)d_out;

    dim3 grid(BB / ROWS);   // 1024 blocks -> 3 per CU -> 6 waves/SIMD, no spill
    dim3 block(BLK);
    lstm_mfma5<<<grid, block, 0, stream>>>(seq, Wih_e, Whh_e, bih_e, bhh_e,
                                           Wih_d, Whh_d, bih_d, bhh_d,
                                           Wl, bl, out);
}

// Round 8
// 385.193 us; speedup vs baseline: 4.6538x; 1.0249x over previous
//
#include <hip/hip_runtime.h>

#define BB 16384
#define SS 200
#define NF 6
#define HH 50
#define TT 5
#define ROWS 16
#define BLK 512
#define SEQ_STRIDE (SS * NF)   // 1200

typedef __attribute__((ext_vector_type(8))) short short8;
typedef __attribute__((ext_vector_type(4))) float f32x4;

__device__ __forceinline__ unsigned short f2bf_rne(float f) {
    unsigned u = __float_as_uint(f);
    u += 0x7FFF + ((u >> 16) & 1);
    return (unsigned short)(u >> 16);
}
__device__ __forceinline__ unsigned short f2bf_t(float f) {
    return (unsigned short)(__float_as_uint(f) >> 16);
}
__device__ __forceinline__ float bf2f(unsigned short h) {
    return __uint_as_float(((unsigned)h) << 16);
}
#define LOG2E 1.44269504088896f
__device__ __forceinline__ float sigm(float x) {
    return __builtin_amdgcn_rcpf(1.0f + __builtin_amdgcn_exp2f(-LOG2E * x));
}
__device__ __forceinline__ float tanh_f(float x) {
    float r = __builtin_amdgcn_rcpf(1.0f + __builtin_amdgcn_exp2f(-2.0f * LOG2E * x));
    return fmaf(2.0f, r, -1.0f);
}

// By-value fragment builder: no address-taken locals -> SROA keeps it in regs.
struct HL { short8 h, l; };
__device__ __forceinline__ HL mk8(const float* __restrict__ Wih,
                                  const float* __restrict__ Whh,
                                  bool valid, int orow, int kbase)
{
    HL r;
    #pragma unroll
    for (int j = 0; j < 8; ++j) {
        int k = kbase + j;
        float v = 0.0f;
        if (valid && k < NF + HH)
            v = (k < NF) ? Wih[orow * NF + k] : Whh[orow * HH + (k - NF)];
        unsigned short hb = f2bf_rne(v);
        r.h[j] = (short)hb;
        r.l[j] = (short)f2bf_rne(v - bf2f(hb));
    }
    return r;
}

__device__ __forceinline__ void cell_upd(const f32x4& g, float& c, int u, int l15,
                                         unsigned short* BhQ, unsigned short* BlQ)
{
    float cc = sigm(g[1]) * c + sigm(g[0]) * tanh_f(g[2]);
    c = cc;
    float hh = sigm(g[3]) * tanh_f(cc);
    if (u < HH) {
        int k = NF + u;
        int pos = (((k >> 5) * 64) + ((k >> 3) & 3) * 16 + l15) * 8 + (k & 7);
        unsigned short hb = f2bf_t(hh);
        BhQ[pos] = hb;
        BlQ[pos] = f2bf_t(hh - bf2f(hb));
    }
}

__global__ __launch_bounds__(BLK, 6) void lstm_mfma6(
    const float* __restrict__ seq,
    const float* __restrict__ Wih_e, const float* __restrict__ Whh_e,
    const float* __restrict__ bih_e, const float* __restrict__ bhh_e,
    const float* __restrict__ Wih_d, const float* __restrict__ Whh_d,
    const float* __restrict__ bih_d, const float* __restrict__ bhh_d,
    const float* __restrict__ Wl, const float* __restrict__ bl,
    float* __restrict__ out)
{
    __shared__ short8 Bh8[256], Bl8[256];   // 2 buffers x 128 chunks (4KB+4KB)
    __shared__ float bs[256];               // fused bias in g2 order
    __shared__ float xs[ROWS * 97];         // 16 steps x 6 feats per row
    __shared__ float Wls[NF * HH];
    __shared__ float bls[NF];

    unsigned short* BhU = (unsigned short*)Bh8;   // buffer P at ushort ofs P*1024
    unsigned short* BlU = (unsigned short*)Bl8;

    const int tid  = threadIdx.x;
    const int w    = tid >> 6;
    const int lane = tid & 63;
    const int q    = lane >> 4;
    const int l15  = lane & 15;
    const int b0   = blockIdx.x * ROWS;
    const int mt0  = w, mt1 = w + 8;        // 13 M-tiles: {0..7} + {8..12}
    const bool has2 = (w < 5);

    // per-lane A-row descriptors (lane kt*16+r holds A[mt*16+r][ks*32+kt*8+j])
    const int r15 = lane & 15, kt = lane >> 4;
    const int g2a = mt0 * 16 + r15, u0a = g2a >> 2;
    const bool v0 = (u0a < HH);
    const int orow0 = (g2a & 3) * HH + u0a;
    const int g2b = mt1 * 16 + r15, u1a = g2b >> 2;
    const bool v1 = has2 && (u1a < HH);
    const int orow1 = (g2b & 3) * HH + u1a;

    // ---- one-time init ----
    {
        unsigned* zh = (unsigned*)Bh8;
        unsigned* zl = (unsigned*)Bl8;
        for (int i = tid; i < 1024; i += BLK) { zh[i] = 0u; zl[i] = 0u; }
    }
    for (int i = tid; i < NF * HH; i += BLK) Wls[i] = Wl[i];
    if (tid < NF) bls[tid] = bl[tid];
    for (int g2 = tid; g2 < 256; g2 += BLK) {
        int u = g2 >> 2, gt = g2 & 3;
        bs[g2] = (u < HH) ? (bih_e[gt * HH + u] + bhh_e[gt * HH + u]) : 0.0f;
    }

    short8 ah00, ah01, al00, al01, ah10, ah11, al10, al11;
    {
        HL t0 = mk8(Wih_e, Whh_e, v0, orow0, kt * 8);
        HL t1 = mk8(Wih_e, Whh_e, v0, orow0, 32 + kt * 8);
        ah00 = t0.h; al00 = t0.l; ah01 = t1.h; al01 = t1.l;
        HL s0 = mk8(Wih_e, Whh_e, v1, orow1, kt * 8);
        HL s1 = mk8(Wih_e, Whh_e, v1, orow1, 32 + kt * 8);
        ah10 = s0.h; al10 = s0.l; ah11 = s1.h; al11 = s1.l;
    }

    // xstage chunk for steps 0..15
    for (int idx = tid; idx < ROWS * 96; idx += BLK) {
        int row = idx / 96, cc = idx - row * 96;
        xs[row * 97 + cc] = seq[(size_t)(b0 + row) * SEQ_STRIDE + cc];
    }
    __syncthreads();

    // prologue: x_0 into buf0 (h-slots already zero = h0)
    if (tid < 96) {
        int row = tid & 15, n = tid >> 4;
        float x = xs[row * 97 + n];
        unsigned short xh = f2bf_rne(x);
        BhU[row * 8 + n] = xh;
        BlU[row * 8 + n] = f2bf_rne(x - bf2f(xh));
    }
    __syncthreads();

    float c0 = 0.0f, c1 = 0.0f;

    for (int t = 0; t < SS + TT; ++t) {
        const int P = t & 1, Q = P ^ 1;
        const int Pofs8 = P * 128;          // short8 offset of read buffer
        unsigned short* BhQ = BhU + Q * 1024;
        unsigned short* BlQ = BlU + Q * 1024;

        if (t == SS) {
            // switch to decoder weights; prior reads fenced by end barrier of SS-1
            HL t0 = mk8(Wih_d, Whh_d, v0, orow0, kt * 8);
            HL t1 = mk8(Wih_d, Whh_d, v0, orow0, 32 + kt * 8);
            ah00 = t0.h; al00 = t0.l; ah01 = t1.h; al01 = t1.l;
            HL s0 = mk8(Wih_d, Whh_d, v1, orow1, kt * 8);
            HL s1 = mk8(Wih_d, Whh_d, v1, orow1, 32 + kt * 8);
            ah10 = s0.h; al10 = s0.l; ah11 = s1.h; al11 = s1.l;
            for (int g2 = tid; g2 < 256; g2 += BLK) {
                int u = g2 >> 2, gt = g2 & 3;
                bs[g2] = (u < HH) ? (bih_d[gt * HH + u] + bhh_d[gt * HH + u]) : 0.0f;
            }
            __syncthreads();
        }
        if ((t & 15) == 15 && t < SS - 1) {
            // refresh xs for steps t+1 .. t+16 (prev reads done at end barrier)
            const int t0 = t + 1;
            for (int idx = tid; idx < ROWS * 96; idx += BLK) {
                int row = idx / 96, cc = idx - row * 96;
                float v = 0.0f;
                if (t0 + cc / 6 < SS)
                    v = seq[(size_t)(b0 + row) * SEQ_STRIDE + t0 * NF + cc];
                xs[row * 97 + cc] = v;
            }
            __syncthreads();
        }

        // ---- MFMA: acc starts at bias (broadcast ds_read_b128) ----
        f32x4 acc0 = *(const f32x4*)&bs[mt0 * 16 + q * 4];
        f32x4 acc1 = has2 ? *(const f32x4*)&bs[mt1 * 16 + q * 4]
                          : (f32x4){0.f, 0.f, 0.f, 0.f};
        {
            short8 bh0 = Bh8[Pofs8 + lane];
            short8 bv0 = Bl8[Pofs8 + lane];
            acc0 = __builtin_amdgcn_mfma_f32_16x16x32_bf16(ah00, bh0, acc0, 0, 0, 0);
            acc0 = __builtin_amdgcn_mfma_f32_16x16x32_bf16(ah00, bv0, acc0, 0, 0, 0);
            acc0 = __builtin_amdgcn_mfma_f32_16x16x32_bf16(al00, bh0, acc0, 0, 0, 0);
            if (has2) {
                acc1 = __builtin_amdgcn_mfma_f32_16x16x32_bf16(ah10, bh0, acc1, 0, 0, 0);
                acc1 = __builtin_amdgcn_mfma_f32_16x16x32_bf16(ah10, bv0, acc1, 0, 0, 0);
                acc1 = __builtin_amdgcn_mfma_f32_16x16x32_bf16(al10, bh0, acc1, 0, 0, 0);
            }
            short8 bh1 = Bh8[Pofs8 + 64 + lane];
            short8 bv1 = Bl8[Pofs8 + 64 + lane];
            acc0 = __builtin_amdgcn_mfma_f32_16x16x32_bf16(ah01, bh1, acc0, 0, 0, 0);
            acc0 = __builtin_amdgcn_mfma_f32_16x16x32_bf16(ah01, bv1, acc0, 0, 0, 0);
            acc0 = __builtin_amdgcn_mfma_f32_16x16x32_bf16(al01, bh1, acc0, 0, 0, 0);
            if (has2) {
                acc1 = __builtin_amdgcn_mfma_f32_16x16x32_bf16(ah11, bh1, acc1, 0, 0, 0);
                acc1 = __builtin_amdgcn_mfma_f32_16x16x32_bf16(ah11, bv1, acc1, 0, 0, 0);
                acc1 = __builtin_amdgcn_mfma_f32_16x16x32_bf16(al11, bh1, acc1, 0, 0, 0);
            }
        }

        // ---- write x_{t+1} into Q (encoder source; t==SS-1 writes dec_in) ----
        if (t < SS && tid < 96) {
            int row = tid & 15, n = tid >> 4;
            int px = (t + 1 < SS) ? t + 1 : SS - 1;
            float x = xs[row * 97 + (px & 15) * NF + n];
            unsigned short xh = f2bf_rne(x);
            BhQ[row * 8 + n] = xh;
            BlQ[row * 8 + n] = f2bf_rne(x - bf2f(xh));
        }

        // ---- lane-local cell update; h_t into Q ----
        cell_upd(acc0, c0, mt0 * 4 + q, l15, BhQ, BlQ);
        if (has2) cell_upd(acc1, c1, mt1 * 4 + q, l15, BhQ, BlQ);

        // ---- decoder: pred from h_t (needs barrier), feed back as x_{t+1} ----
        if (t >= SS) {
            __syncthreads();   // h_t visible in Q
            if (tid < 96) {
                int row = tid & 15, n = tid >> 4;
                float a = bls[n];
                #pragma unroll
                for (int u2 = 0; u2 < HH; ++u2) {
                    int k = NF + u2;
                    int pos = ((k >> 5) * 64 + ((k >> 3) & 3) * 16 + row) * 8 + (k & 7);
                    float hv = bf2f(BhQ[pos]) + bf2f(BlQ[pos]);
                    a = fmaf(Wls[n * HH + u2], hv, a);
                }
                out[(size_t)(b0 + row) * (TT * NF) + (t - SS) * NF + n] = a;
                unsigned short ab = f2bf_rne(a);
                BhQ[row * 8 + n] = ab;
                BlQ[row * 8 + n] = f2bf_rne(a - bf2f(ab));
            }
        }

        __syncthreads();       // Q complete; P free for reuse next step
    }
}

extern "C" void kernel_launch(void* const* d_in, const int* in_sizes, int n_in,
                              void* d_out, int out_size, void* d_ws, size_t ws_size,
                              hipStream_t stream)
{
    const float* seq   = (const float*)d_in[0];
    const float* Wih_e = (const float*)d_in[1];
    const float* Whh_e = (const float*)d_in[2];
    const float* bih_e = (const float*)d_in[3];
    const float* bhh_e = (const float*)d_in[4];
    const float* Wih_d = (const float*)d_in[5];
    const float* Whh_d = (const float*)d_in[6];
    const float* bih_d = (const float*)d_in[7];
    const float* bhh_d = (const float*)d_in[8];
    const float* Wl    = (const float*)d_in[9];
    const float* bl    = (const float*)d_in[10];
    float* out = (float*)d_out;

    dim3 grid(BB / ROWS);   // 1024 blocks -> 3 per CU at 6 waves/SIMD
    dim3 block(BLK);
    lstm_mfma6<<<grid, block, 0, stream>>>(seq, Wih_e, Whh_e, bih_e, bhh_e,
                                           Wih_d, Whh_d, bih_d, bhh_d,
                                           Wl, bl, out);
}

// Round 9
// 374.163 us; speedup vs baseline: 4.7910x; 1.0295x over previous
//
#include <hip/hip_runtime.h>

#define BB 16384
#define SS 200
#define NF 6
#define HH 50
#define TT 5
#define ROWS 16
#define BLK 256
#define SEQ_STRIDE (SS * NF)   // 1200

typedef __attribute__((ext_vector_type(8))) short short8;
typedef __attribute__((ext_vector_type(4))) float f32x4;

__device__ __forceinline__ unsigned short f2bf_rne(float f) {
    unsigned u = __float_as_uint(f);
    u += 0x7FFF + ((u >> 16) & 1);
    return (unsigned short)(u >> 16);
}
__device__ __forceinline__ unsigned short f2bf_t(float f) {
    return (unsigned short)(__float_as_uint(f) >> 16);
}
__device__ __forceinline__ float bf2f(unsigned short h) {
    return __uint_as_float(((unsigned)h) << 16);
}
#define LOG2E 1.44269504088896f
__device__ __forceinline__ float sigm(float x) {
    return __builtin_amdgcn_rcpf(1.0f + __builtin_amdgcn_exp2f(-LOG2E * x));
}
__device__ __forceinline__ float tanh_f(float x) {
    float r = __builtin_amdgcn_rcpf(1.0f + __builtin_amdgcn_exp2f(-2.0f * LOG2E * x));
    return fmaf(2.0f, r, -1.0f);
}

// By-value fragment builder: no address-taken locals -> stays in registers.
struct HL { short8 h, l; };
__device__ __forceinline__ HL mk8(const float* __restrict__ Wih,
                                  const float* __restrict__ Whh,
                                  bool valid, int orow, int kbase)
{
    HL r;
    #pragma unroll
    for (int j = 0; j < 8; ++j) {
        int k = kbase + j;
        float v = 0.0f;
        if (valid && k < NF + HH)
            v = (k < NF) ? Wih[orow * NF + k] : Whh[orow * HH + (k - NF)];
        unsigned short hb = f2bf_rne(v);
        r.h[j] = (short)hb;
        r.l[j] = (short)f2bf_rne(v - bf2f(hb));
    }
    return r;
}

__device__ __forceinline__ void cell_upd(const f32x4& g, float& c, int u, int l15,
                                         unsigned short* BhQ, unsigned short* BlQ)
{
    float cc = sigm(g[1]) * c + sigm(g[0]) * tanh_f(g[2]);
    c = cc;
    float hh = sigm(g[3]) * tanh_f(cc);
    if (u < HH) {
        int k = NF + u;
        int pos = (((k >> 5) * 64) + ((k >> 3) & 3) * 16 + l15) * 8 + (k & 7);
        unsigned short hb = f2bf_t(hh);
        BhQ[pos] = hb;
        BlQ[pos] = f2bf_t(hh - bf2f(hb));
    }
}

#define MFMA3(acc, ah, al, bh, bv)                                            \
    acc = __builtin_amdgcn_mfma_f32_16x16x32_bf16(ah, bh, acc, 0, 0, 0);      \
    acc = __builtin_amdgcn_mfma_f32_16x16x32_bf16(ah, bv, acc, 0, 0, 0);      \
    acc = __builtin_amdgcn_mfma_f32_16x16x32_bf16(al, bh, acc, 0, 0, 0);

__global__ __launch_bounds__(BLK, 4) void lstm_mfma7(
    const float* __restrict__ seq,
    const float* __restrict__ Wih_e, const float* __restrict__ Whh_e,
    const float* __restrict__ bih_e, const float* __restrict__ bhh_e,
    const float* __restrict__ Wih_d, const float* __restrict__ Whh_d,
    const float* __restrict__ bih_d, const float* __restrict__ bhh_d,
    const float* __restrict__ Wl, const float* __restrict__ bl,
    float* __restrict__ out)
{
    __shared__ short8 Bh8[256], Bl8[256];   // 2 buffers x 128 chunks (4KB+4KB)
    __shared__ float bs[256];               // fused bias in g2 order
    __shared__ float xs[ROWS * 97];         // 16 steps x 6 feats per row
    __shared__ float Wls[NF * HH];
    __shared__ float bls[NF];

    unsigned short* BhU = (unsigned short*)Bh8;   // buffer P at ushort ofs P*1024
    unsigned short* BlU = (unsigned short*)Bl8;

    const int tid  = threadIdx.x;
    const int w    = tid >> 6;              // 4 waves
    const int lane = tid & 63;
    const int q    = lane >> 4;
    const int l15  = lane & 15;
    const int b0   = blockIdx.x * ROWS;
    // M-tiles per wave: {w, w+4, w+8} + tile 12 for wave 0 (13 real tiles)
    const int tA = w, tB = w + 4, tC = w + 8, tD = w + 12;
    const bool hasD = (w == 0);

    // per-lane A-row descriptors (lane kt*16+r holds A[mt*16+r][ks*32+kt*8+j])
    const int r15 = lane & 15, kt = lane >> 4;
    const int g2A = tA * 16 + r15, uA_ = g2A >> 2;
    const int g2B = tB * 16 + r15, uB_ = g2B >> 2;
    const int g2C = tC * 16 + r15, uC_ = g2C >> 2;
    const int g2D = tD * 16 + r15, uD_ = g2D >> 2;
    const bool vA = (uA_ < HH), vB = (uB_ < HH), vC = (uC_ < HH);
    const bool vD = hasD && (uD_ < HH);
    const int oA = (g2A & 3) * HH + uA_, oB = (g2B & 3) * HH + uB_;
    const int oC = (g2C & 3) * HH + uC_, oD = (g2D & 3) * HH + uD_;

    // ---- one-time init ----
    {
        unsigned* zh = (unsigned*)Bh8;
        unsigned* zl = (unsigned*)Bl8;
        for (int i = tid; i < 1024; i += BLK) { zh[i] = 0u; zl[i] = 0u; }
    }
    for (int i = tid; i < NF * HH; i += BLK) Wls[i] = Wl[i];
    if (tid < NF) bls[tid] = bl[tid];
    for (int g2 = tid; g2 < 256; g2 += BLK) {
        int u = g2 >> 2, gt = g2 & 3;
        bs[g2] = (u < HH) ? (bih_e[gt * HH + u] + bhh_e[gt * HH + u]) : 0.0f;
    }

    short8 ahA0, ahA1, alA0, alA1, ahB0, ahB1, alB0, alB1;
    short8 ahC0, ahC1, alC0, alC1, ahD0, ahD1, alD0, alD1;
    {
        HL x0 = mk8(Wih_e, Whh_e, vA, oA, kt * 8);
        HL x1 = mk8(Wih_e, Whh_e, vA, oA, 32 + kt * 8);
        ahA0 = x0.h; alA0 = x0.l; ahA1 = x1.h; alA1 = x1.l;
        HL y0 = mk8(Wih_e, Whh_e, vB, oB, kt * 8);
        HL y1 = mk8(Wih_e, Whh_e, vB, oB, 32 + kt * 8);
        ahB0 = y0.h; alB0 = y0.l; ahB1 = y1.h; alB1 = y1.l;
        HL z0 = mk8(Wih_e, Whh_e, vC, oC, kt * 8);
        HL z1 = mk8(Wih_e, Whh_e, vC, oC, 32 + kt * 8);
        ahC0 = z0.h; alC0 = z0.l; ahC1 = z1.h; alC1 = z1.l;
        HL u0 = mk8(Wih_e, Whh_e, vD, oD, kt * 8);
        HL u1 = mk8(Wih_e, Whh_e, vD, oD, 32 + kt * 8);
        ahD0 = u0.h; alD0 = u0.l; ahD1 = u1.h; alD1 = u1.l;
    }

    // xstage chunk for steps 0..15
    for (int idx = tid; idx < ROWS * 96; idx += BLK) {
        int row = idx / 96, cc = idx - row * 96;
        xs[row * 97 + cc] = seq[(size_t)(b0 + row) * SEQ_STRIDE + cc];
    }
    __syncthreads();

    // prologue: x_0 into buf0 (h-slots already zero = h0)
    if (tid < 96) {
        int row = tid & 15, n = tid >> 4;
        float x = xs[row * 97 + n];
        unsigned short xh = f2bf_rne(x);
        BhU[row * 8 + n] = xh;
        BlU[row * 8 + n] = f2bf_rne(x - bf2f(xh));
    }
    __syncthreads();

    float cA = 0.0f, cB = 0.0f, cC = 0.0f, cD = 0.0f;

    for (int t = 0; t < SS + TT; ++t) {
        const int P = t & 1, Q = P ^ 1;
        const int Pofs8 = P * 128;          // short8 offset of read buffer
        unsigned short* BhQ = BhU + Q * 1024;
        unsigned short* BlQ = BlU + Q * 1024;

        if (t == SS) {
            // switch to decoder weights; prior reads fenced by end barrier of SS-1
            HL x0 = mk8(Wih_d, Whh_d, vA, oA, kt * 8);
            HL x1 = mk8(Wih_d, Whh_d, vA, oA, 32 + kt * 8);
            ahA0 = x0.h; alA0 = x0.l; ahA1 = x1.h; alA1 = x1.l;
            HL y0 = mk8(Wih_d, Whh_d, vB, oB, kt * 8);
            HL y1 = mk8(Wih_d, Whh_d, vB, oB, 32 + kt * 8);
            ahB0 = y0.h; alB0 = y0.l; ahB1 = y1.h; alB1 = y1.l;
            HL z0 = mk8(Wih_d, Whh_d, vC, oC, kt * 8);
            HL z1 = mk8(Wih_d, Whh_d, vC, oC, 32 + kt * 8);
            ahC0 = z0.h; alC0 = z0.l; ahC1 = z1.h; alC1 = z1.l;
            HL u0 = mk8(Wih_d, Whh_d, vD, oD, kt * 8);
            HL u1 = mk8(Wih_d, Whh_d, vD, oD, 32 + kt * 8);
            ahD0 = u0.h; alD0 = u0.l; ahD1 = u1.h; alD1 = u1.l;
            for (int g2 = tid; g2 < 256; g2 += BLK) {
                int u = g2 >> 2, gt = g2 & 3;
                bs[g2] = (u < HH) ? (bih_d[gt * HH + u] + bhh_d[gt * HH + u]) : 0.0f;
            }
            __syncthreads();
        }
        if ((t & 15) == 15 && t < SS - 1) {
            // refresh xs for steps t+1 .. t+16 (prev reads done at end barrier)
            const int t0 = t + 1;
            for (int idx = tid; idx < ROWS * 96; idx += BLK) {
                int row = idx / 96, cc = idx - row * 96;
                float v = 0.0f;
                if (t0 + cc / 6 < SS)
                    v = seq[(size_t)(b0 + row) * SEQ_STRIDE + t0 * NF + cc];
                xs[row * 97 + cc] = v;
            }
            __syncthreads();
        }

        // ---- MFMA: acc starts at bias (broadcast ds_read_b128) ----
        f32x4 accA = *(const f32x4*)&bs[tA * 16 + q * 4];
        f32x4 accB = *(const f32x4*)&bs[tB * 16 + q * 4];
        f32x4 accC = *(const f32x4*)&bs[tC * 16 + q * 4];
        f32x4 accD = hasD ? *(const f32x4*)&bs[tD * 16 + q * 4]
                          : (f32x4){0.f, 0.f, 0.f, 0.f};
        {
            short8 bh0 = Bh8[Pofs8 + lane];
            short8 bv0 = Bl8[Pofs8 + lane];
            MFMA3(accA, ahA0, alA0, bh0, bv0)
            MFMA3(accB, ahB0, alB0, bh0, bv0)
            MFMA3(accC, ahC0, alC0, bh0, bv0)
            if (hasD) { MFMA3(accD, ahD0, alD0, bh0, bv0) }
            short8 bh1 = Bh8[Pofs8 + 64 + lane];
            short8 bv1 = Bl8[Pofs8 + 64 + lane];
            MFMA3(accA, ahA1, alA1, bh1, bv1)
            MFMA3(accB, ahB1, alB1, bh1, bv1)
            MFMA3(accC, ahC1, alC1, bh1, bv1)
            if (hasD) { MFMA3(accD, ahD1, alD1, bh1, bv1) }
        }

        // ---- write x_{t+1} into Q (encoder source; t==SS-1 writes dec_in) ----
        if (t < SS && tid < 96) {
            int row = tid & 15, n = tid >> 4;
            int px = (t + 1 < SS) ? t + 1 : SS - 1;
            float x = xs[row * 97 + (px & 15) * NF + n];
            unsigned short xh = f2bf_rne(x);
            BhQ[row * 8 + n] = xh;
            BlQ[row * 8 + n] = f2bf_rne(x - bf2f(xh));
        }

        // ---- lane-local cell update; h_t into Q ----
        cell_upd(accA, cA, tA * 4 + q, l15, BhQ, BlQ);
        cell_upd(accB, cB, tB * 4 + q, l15, BhQ, BlQ);
        cell_upd(accC, cC, tC * 4 + q, l15, BhQ, BlQ);
        if (hasD) cell_upd(accD, cD, tD * 4 + q, l15, BhQ, BlQ);

        // ---- decoder: pred from h_t (needs barrier), feed back as x_{t+1} ----
        if (t >= SS) {
            __syncthreads();   // h_t visible in Q
            if (tid < 96) {
                int row = tid & 15, n = tid >> 4;
                float a = bls[n];
                #pragma unroll
                for (int u2 = 0; u2 < HH; ++u2) {
                    int k = NF + u2;
                    int pos = ((k >> 5) * 64 + ((k >> 3) & 3) * 16 + row) * 8 + (k & 7);
                    float hv = bf2f(BhQ[pos]) + bf2f(BlQ[pos]);
                    a = fmaf(Wls[n * HH + u2], hv, a);
                }
                out[(size_t)(b0 + row) * (TT * NF) + (t - SS) * NF + n] = a;
                unsigned short ab = f2bf_rne(a);
                BhQ[row * 8 + n] = ab;
                BlQ[row * 8 + n] = f2bf_rne(a - bf2f(ab));
            }
        }

        __syncthreads();       // Q complete; P free for reuse next step
    }
}

extern "C" void kernel_launch(void* const* d_in, const int* in_sizes, int n_in,
                              void* d_out, int out_size, void* d_ws, size_t ws_size,
                              hipStream_t stream)
{
    const float* seq   = (const float*)d_in[0];
    const float* Wih_e = (const float*)d_in[1];
    const float* Whh_e = (const float*)d_in[2];
    const float* bih_e = (const float*)d_in[3];
    const float* bhh_e = (const float*)d_in[4];
    const float* Wih_d = (const float*)d_in[5];
    const float* Whh_d = (const float*)d_in[6];
    const float* bih_d = (const float*)d_in[7];
    const float* bhh_d = (const float*)d_in[8];
    const float* Wl    = (const float*)d_in[9];
    const float* bl    = (const float*)d_in[10];
    float* out = (float*)d_out;

    dim3 grid(BB / ROWS);   // 1024 blocks -> 4 per CU, single pass
    dim3 block(BLK);        // 4 waves
    lstm_mfma7<<<grid, block, 0, stream>>>(seq, Wih_e, Whh_e, bih_e, bhh_e,
                                           Wih_d, Whh_d, bih_d, bhh_d,
                                           Wl, bl, out);
}

// Round 10
// 357.163 us; speedup vs baseline: 5.0190x; 1.0476x over previous
//
#include <hip/hip_runtime.h>

#define BB 16384
#define SS 200
#define NF 6
#define HH 50
#define TT 5
#define ROWS 16
#define BLK 256
#define SEQ_STRIDE (SS * NF)   // 1200

typedef _Float16 half8 __attribute__((ext_vector_type(8)));
typedef __attribute__((ext_vector_type(4))) float f32x4;

#define LOG2E 1.44269504088896f
__device__ __forceinline__ float sigm(float x) {
    return __builtin_amdgcn_rcpf(1.0f + __builtin_amdgcn_exp2f(-LOG2E * x));
}
__device__ __forceinline__ float tanh_f(float x) {
    float r = __builtin_amdgcn_rcpf(1.0f + __builtin_amdgcn_exp2f(-2.0f * LOG2E * x));
    return fmaf(2.0f, r, -1.0f);
}

__device__ __forceinline__ unsigned short h_bits(_Float16 h) {
    return __builtin_bit_cast(unsigned short, h);
}
__device__ __forceinline__ float h_f(unsigned short b) {
    return (float)__builtin_bit_cast(_Float16, b);
}
// fp16 hi/lo split store (hi = RNE fp16, lo = RNE fp16 of residual)
__device__ __forceinline__ void store_hl(unsigned short* Bh, unsigned short* Bl,
                                         int pos, float x)
{
    _Float16 h = (_Float16)x;
    float lo = x - (float)h;
    Bh[pos] = h_bits(h);
    Bl[pos] = h_bits((_Float16)lo);
}

// Single-fp16 weight fragment for 8 consecutive k of one A-row (by value).
__device__ __forceinline__ half8 mk8h(const float* __restrict__ Wih,
                                      const float* __restrict__ Whh,
                                      bool valid, int orow, int kbase)
{
    half8 r;
    #pragma unroll
    for (int j = 0; j < 8; ++j) {
        int k = kbase + j;
        float v = 0.0f;
        if (valid && k < NF + HH)
            v = (k < NF) ? Wih[orow * NF + k] : Whh[orow * HH + (k - NF)];
        r[j] = (_Float16)v;
    }
    return r;
}

__device__ __forceinline__ void cell_upd(const f32x4& g, float& c, int u, int l15,
                                         unsigned short* BhQ, unsigned short* BlQ)
{
    float cc = sigm(g[1]) * c + sigm(g[0]) * tanh_f(g[2]);
    c = cc;
    float hh = sigm(g[3]) * tanh_f(cc);
    if (u < HH) {
        int k = NF + u;
        int pos = (((k >> 5) * 64) + ((k >> 3) & 3) * 16 + l15) * 8 + (k & 7);
        store_hl(BhQ, BlQ, pos, hh);
    }
}

#define MFMA2(acc, a, bh, bv)                                                 \
    acc = __builtin_amdgcn_mfma_f32_16x16x32_f16(a, bh, acc, 0, 0, 0);        \
    acc = __builtin_amdgcn_mfma_f32_16x16x32_f16(a, bv, acc, 0, 0, 0);

__global__ __launch_bounds__(BLK, 4) void lstm_mfma8(
    const float* __restrict__ seq,
    const float* __restrict__ Wih_e, const float* __restrict__ Whh_e,
    const float* __restrict__ bih_e, const float* __restrict__ bhh_e,
    const float* __restrict__ Wih_d, const float* __restrict__ Whh_d,
    const float* __restrict__ bih_d, const float* __restrict__ bhh_d,
    const float* __restrict__ Wl, const float* __restrict__ bl,
    float* __restrict__ out)
{
    __shared__ half8 Bh8[256], Bl8[256];    // 2 buffers x 128 chunks (4KB+4KB)
    __shared__ float bs[256];               // fused bias in g2 order
    __shared__ float xs[ROWS * 97];         // 16 steps x 6 feats per row
    __shared__ float Wls[NF * HH];
    __shared__ float bls[NF];

    unsigned short* BhU = (unsigned short*)Bh8;   // buffer P at ushort ofs P*1024
    unsigned short* BlU = (unsigned short*)Bl8;

    const int tid  = threadIdx.x;
    const int w    = tid >> 6;              // 4 waves
    const int lane = tid & 63;
    const int q    = lane >> 4;
    const int l15  = lane & 15;
    const int b0   = blockIdx.x * ROWS;
    // M-tiles per wave: {w, w+4, w+8} + tile 12 for wave 0 (13 real tiles)
    const int tA = w, tB = w + 4, tC = w + 8, tD = w + 12;
    const bool hasD = (w == 0);

    // per-lane A-row descriptors (lane kt*16+r holds A[mt*16+r][ks*32+kt*8+j])
    const int r15 = lane & 15, kt = lane >> 4;
    const int g2A = tA * 16 + r15, uA_ = g2A >> 2;
    const int g2B = tB * 16 + r15, uB_ = g2B >> 2;
    const int g2C = tC * 16 + r15, uC_ = g2C >> 2;
    const int g2D = tD * 16 + r15, uD_ = g2D >> 2;
    const bool vA = (uA_ < HH), vB = (uB_ < HH), vC = (uC_ < HH);
    const bool vD = hasD && (uD_ < HH);
    const int oA = (g2A & 3) * HH + uA_, oB = (g2B & 3) * HH + uB_;
    const int oC = (g2C & 3) * HH + uC_, oD = (g2D & 3) * HH + uD_;

    // ---- one-time init ----
    {
        unsigned* zh = (unsigned*)Bh8;
        unsigned* zl = (unsigned*)Bl8;
        for (int i = tid; i < 1024; i += BLK) { zh[i] = 0u; zl[i] = 0u; }
    }
    for (int i = tid; i < NF * HH; i += BLK) Wls[i] = Wl[i];
    if (tid < NF) bls[tid] = bl[tid];
    for (int g2 = tid; g2 < 256; g2 += BLK) {
        int u = g2 >> 2, gt = g2 & 3;
        bs[g2] = (u < HH) ? (bih_e[gt * HH + u] + bhh_e[gt * HH + u]) : 0.0f;
    }

    half8 aA0, aA1, aB0, aB1, aC0, aC1, aD0, aD1;
    aA0 = mk8h(Wih_e, Whh_e, vA, oA, kt * 8);
    aA1 = mk8h(Wih_e, Whh_e, vA, oA, 32 + kt * 8);
    aB0 = mk8h(Wih_e, Whh_e, vB, oB, kt * 8);
    aB1 = mk8h(Wih_e, Whh_e, vB, oB, 32 + kt * 8);
    aC0 = mk8h(Wih_e, Whh_e, vC, oC, kt * 8);
    aC1 = mk8h(Wih_e, Whh_e, vC, oC, 32 + kt * 8);
    aD0 = mk8h(Wih_e, Whh_e, vD, oD, kt * 8);
    aD1 = mk8h(Wih_e, Whh_e, vD, oD, 32 + kt * 8);

    // xstage chunk for steps 0..15
    for (int idx = tid; idx < ROWS * 96; idx += BLK) {
        int row = idx / 96, cc = idx - row * 96;
        xs[row * 97 + cc] = seq[(size_t)(b0 + row) * SEQ_STRIDE + cc];
    }
    __syncthreads();

    // prologue: x_0 into buf0 (h-slots already zero = h0)
    if (tid < 96) {
        int row = tid & 15, n = tid >> 4;
        store_hl(BhU, BlU, row * 8 + n, xs[row * 97 + n]);
    }
    __syncthreads();

    float cA = 0.0f, cB = 0.0f, cC = 0.0f, cD = 0.0f;

    for (int t = 0; t < SS + TT; ++t) {
        const int P = t & 1, Q = P ^ 1;
        const int Pofs8 = P * 128;          // half8 offset of read buffer
        unsigned short* BhQ = BhU + Q * 1024;
        unsigned short* BlQ = BlU + Q * 1024;

        if (t == SS) {
            // switch to decoder weights; prior reads fenced by end barrier of SS-1
            aA0 = mk8h(Wih_d, Whh_d, vA, oA, kt * 8);
            aA1 = mk8h(Wih_d, Whh_d, vA, oA, 32 + kt * 8);
            aB0 = mk8h(Wih_d, Whh_d, vB, oB, kt * 8);
            aB1 = mk8h(Wih_d, Whh_d, vB, oB, 32 + kt * 8);
            aC0 = mk8h(Wih_d, Whh_d, vC, oC, kt * 8);
            aC1 = mk8h(Wih_d, Whh_d, vC, oC, 32 + kt * 8);
            aD0 = mk8h(Wih_d, Whh_d, vD, oD, kt * 8);
            aD1 = mk8h(Wih_d, Whh_d, vD, oD, 32 + kt * 8);
            for (int g2 = tid; g2 < 256; g2 += BLK) {
                int u = g2 >> 2, gt = g2 & 3;
                bs[g2] = (u < HH) ? (bih_d[gt * HH + u] + bhh_d[gt * HH + u]) : 0.0f;
            }
            __syncthreads();
        }
        if ((t & 15) == 15 && t < SS - 1) {
            // refresh xs for steps t+1 .. t+16 (prev reads done at end barrier)
            const int t0 = t + 1;
            for (int idx = tid; idx < ROWS * 96; idx += BLK) {
                int row = idx / 96, cc = idx - row * 96;
                float v = 0.0f;
                if (t0 + cc / 6 < SS)
                    v = seq[(size_t)(b0 + row) * SEQ_STRIDE + t0 * NF + cc];
                xs[row * 97 + cc] = v;
            }
            __syncthreads();
        }

        // ---- MFMA: acc starts at bias (broadcast ds_read_b128) ----
        f32x4 accA = *(const f32x4*)&bs[tA * 16 + q * 4];
        f32x4 accB = *(const f32x4*)&bs[tB * 16 + q * 4];
        f32x4 accC = *(const f32x4*)&bs[tC * 16 + q * 4];
        f32x4 accD = hasD ? *(const f32x4*)&bs[tD * 16 + q * 4]
                          : (f32x4){0.f, 0.f, 0.f, 0.f};
        {
            half8 bh0 = Bh8[Pofs8 + lane];
            half8 bv0 = Bl8[Pofs8 + lane];
            MFMA2(accA, aA0, bh0, bv0)
            MFMA2(accB, aB0, bh0, bv0)
            MFMA2(accC, aC0, bh0, bv0)
            if (hasD) { MFMA2(accD, aD0, bh0, bv0) }
            half8 bh1 = Bh8[Pofs8 + 64 + lane];
            half8 bv1 = Bl8[Pofs8 + 64 + lane];
            MFMA2(accA, aA1, bh1, bv1)
            MFMA2(accB, aB1, bh1, bv1)
            MFMA2(accC, aC1, bh1, bv1)
            if (hasD) { MFMA2(accD, aD1, bh1, bv1) }
        }

        // ---- write x_{t+1} into Q (encoder source; t==SS-1 writes dec_in) ----
        if (t < SS && tid < 96) {
            int row = tid & 15, n = tid >> 4;
            int px = (t + 1 < SS) ? t + 1 : SS - 1;
            store_hl(BhQ, BlQ, row * 8 + n, xs[row * 97 + (px & 15) * NF + n]);
        }

        // ---- lane-local cell update; h_t into Q ----
        cell_upd(accA, cA, tA * 4 + q, l15, BhQ, BlQ);
        cell_upd(accB, cB, tB * 4 + q, l15, BhQ, BlQ);
        cell_upd(accC, cC, tC * 4 + q, l15, BhQ, BlQ);
        if (hasD) cell_upd(accD, cD, tD * 4 + q, l15, BhQ, BlQ);

        // ---- decoder: pred from h_t (needs barrier), feed back as x_{t+1} ----
        if (t >= SS) {
            __syncthreads();   // h_t visible in Q
            if (tid < 96) {
                int row = tid & 15, n = tid >> 4;
                float a = bls[n];
                #pragma unroll
                for (int u2 = 0; u2 < HH; ++u2) {
                    int k = NF + u2;
                    int pos = ((k >> 5) * 64 + ((k >> 3) & 3) * 16 + row) * 8 + (k & 7);
                    float hv = h_f(BhQ[pos]) + h_f(BlQ[pos]);
                    a = fmaf(Wls[n * HH + u2], hv, a);
                }
                out[(size_t)(b0 + row) * (TT * NF) + (t - SS) * NF + n] = a;
                store_hl(BhQ, BlQ, row * 8 + n, a);
            }
        }

        __syncthreads();       // Q complete; P free for reuse next step
    }
}

extern "C" void kernel_launch(void* const* d_in, const int* in_sizes, int n_in,
                              void* d_out, int out_size, void* d_ws, size_t ws_size,
                              hipStream_t stream)
{
    const float* seq   = (const float*)d_in[0];
    const float* Wih_e = (const float*)d_in[1];
    const float* Whh_e = (const float*)d_in[2];
    const float* bih_e = (const float*)d_in[3];
    const float* bhh_e = (const float*)d_in[4];
    const float* Wih_d = (const float*)d_in[5];
    const float* Whh_d = (const float*)d_in[6];
    const float* bih_d = (const float*)d_in[7];
    const float* bhh_d = (const float*)d_in[8];
    const float* Wl    = (const float*)d_in[9];
    const float* bl    = (const float*)d_in[10];
    float* out = (float*)d_out;

    dim3 grid(BB / ROWS);   // 1024 blocks -> 4 per CU, single pass
    dim3 block(BLK);        // 4 waves
    lstm_mfma8<<<grid, block, 0, stream>>>(seq, Wih_e, Whh_e, bih_e, bhh_e,
                                           Wih_d, Whh_d, bih_d, bhh_d,
                                           Wl, bl, out);
}

// Round 11
// 286.671 us; speedup vs baseline: 6.2532x; 1.2459x over previous
//
#include <hip/hip_runtime.h>

#define BB 16384
#define SS 200
#define NF 6
#define HH 50
#define TT 5
#define ROWS 16
#define BLK 256
#define SEQ_STRIDE (SS * NF)   // 1200

typedef _Float16 half8 __attribute__((ext_vector_type(8)));
typedef __attribute__((ext_vector_type(4))) float f32x4;

#define LOG2E 1.44269504088896f

__device__ __forceinline__ unsigned short h_bits(_Float16 h) {
    return __builtin_bit_cast(unsigned short, h);
}
__device__ __forceinline__ float h_f(unsigned short b) {
    return (float)__builtin_bit_cast(_Float16, b);
}

// Weight fragment for 8 consecutive k of one A-row, PRE-SCALED so the MFMA
// output is directly the exp2 argument:
//   gates i,f,o: s = -log2e * gate   -> sigma = rcp(1+exp2(s))
//   gate  g    : s = -2log2e * g     -> tanh  = 2*rcp(1+exp2(s)) - 1
__device__ __forceinline__ half8 mk8h(const float* __restrict__ Wih,
                                      const float* __restrict__ Whh,
                                      bool valid, int orow, float rscale, int kbase)
{
    half8 r;
    #pragma unroll
    for (int j = 0; j < 8; ++j) {
        int k = kbase + j;
        float v = 0.0f;
        if (valid && k < NF + HH)
            v = (k < NF) ? Wih[orow * NF + k] : Whh[orow * HH + (k - NF)];
        r[j] = (_Float16)(v * rscale);
    }
    return r;
}

// Pre-scaled cell update; stores h (fp16) at precomputed offset posQ.
__device__ __forceinline__ void cell_upd(const f32x4& g, float& c, bool real,
                                         int posQ, unsigned short* BhQ)
{
    float si = __builtin_amdgcn_rcpf(1.0f + __builtin_amdgcn_exp2f(g[0]));
    float sf = __builtin_amdgcn_rcpf(1.0f + __builtin_amdgcn_exp2f(g[1]));
    float tg = fmaf(2.0f, __builtin_amdgcn_rcpf(1.0f + __builtin_amdgcn_exp2f(g[2])), -1.0f);
    float so = __builtin_amdgcn_rcpf(1.0f + __builtin_amdgcn_exp2f(g[3]));
    float cc = sf * c + si * tg;
    c = cc;
    float tc = fmaf(2.0f, __builtin_amdgcn_rcpf(1.0f +
                    __builtin_amdgcn_exp2f(-2.0f * LOG2E * cc)), -1.0f);
    float hh = so * tc;
    if (real) BhQ[posQ] = h_bits((_Float16)hh);
}

__global__ __launch_bounds__(BLK, 4) void lstm_mfma9(
    const float* __restrict__ seq,
    const float* __restrict__ Wih_e, const float* __restrict__ Whh_e,
    const float* __restrict__ bih_e, const float* __restrict__ bhh_e,
    const float* __restrict__ Wih_d, const float* __restrict__ Whh_d,
    const float* __restrict__ bih_d, const float* __restrict__ bhh_d,
    const float* __restrict__ Wl, const float* __restrict__ bl,
    float* __restrict__ out)
{
    __shared__ half8 Bh8[256];              // 2 buffers x 128 chunks (4KB)
    __shared__ float bs[256];               // fused pre-scaled bias, g2 order
    __shared__ float xs[ROWS * 97];         // 16 steps x 6 feats per row
    __shared__ float Wls[NF * HH];
    __shared__ float bls[NF];

    unsigned short* BhU = (unsigned short*)Bh8;   // buffer P at ushort ofs P*1024

    const int tid  = threadIdx.x;
    const int w    = tid >> 6;              // 4 waves
    const int lane = tid & 63;
    const int q    = lane >> 4;
    const int l15  = lane & 15;
    const int b0   = blockIdx.x * ROWS;
    // M-tiles per wave: {w, w+4, w+8} + tile 12 for wave 0 (13 real tiles)
    const int tA = w, tB = w + 4, tC = w + 8, tD = w + 12;
    const bool hasD = (w == 0);

    // per-lane A-row descriptors (lane kt*16+r holds A[mt*16+r][ks*32+kt*8+j])
    const int r15 = lane & 15, kt = lane >> 4;
    const int g2A = tA * 16 + r15, uAr = g2A >> 2;
    const int g2B = tB * 16 + r15, uBr = g2B >> 2;
    const int g2C = tC * 16 + r15, uCr = g2C >> 2;
    const int g2D = tD * 16 + r15, uDr = g2D >> 2;
    const bool vA = (uAr < HH), vB = (uBr < HH), vC = (uCr < HH);
    const bool vD = hasD && (uDr < HH);
    const int oA = (g2A & 3) * HH + uAr, oB = (g2B & 3) * HH + uBr;
    const int oC = (g2C & 3) * HH + uCr, oD = (g2D & 3) * HH + uDr;
    const float scA = ((g2A & 3) == 2) ? -2.0f * LOG2E : -LOG2E;
    const float scB = ((g2B & 3) == 2) ? -2.0f * LOG2E : -LOG2E;
    const float scC = ((g2C & 3) == 2) ? -2.0f * LOG2E : -LOG2E;
    const float scD = ((g2D & 3) == 2) ? -2.0f * LOG2E : -LOG2E;

    // per-lane h-store offsets (unit -> B slot), hoisted out of the t-loop
    const int uA = tA * 4 + q, uB = tB * 4 + q, uC = tC * 4 + q, uD = tD * 4 + q;
    #define HPOS(u) (((((NF + (u)) >> 5) * 64) + (((NF + (u)) >> 3) & 3) * 16 + l15) * 8 + ((NF + (u)) & 7))
    const int posA = HPOS(uA), posB = HPOS(uB), posC = HPOS(uC), posD = HPOS(uD);
    const bool rA = (uA < HH), rB = (uB < HH), rC = (uC < HH);
    const bool rD = hasD && (uD < HH);

    // ---- one-time init ----
    {
        unsigned* zh = (unsigned*)Bh8;
        for (int i = tid; i < 1024; i += BLK) zh[i] = 0u;
    }
    for (int i = tid; i < NF * HH; i += BLK) Wls[i] = Wl[i];
    if (tid < NF) bls[tid] = bl[tid];
    for (int g2 = tid; g2 < 256; g2 += BLK) {
        int u = g2 >> 2, gt = g2 & 3;
        float sc = (gt == 2) ? -2.0f * LOG2E : -LOG2E;
        bs[g2] = (u < HH) ? sc * (bih_e[gt * HH + u] + bhh_e[gt * HH + u]) : 0.0f;
    }

    half8 aA0, aA1, aB0, aB1, aC0, aC1, aD0, aD1;
    aA0 = mk8h(Wih_e, Whh_e, vA, oA, scA, kt * 8);
    aA1 = mk8h(Wih_e, Whh_e, vA, oA, scA, 32 + kt * 8);
    aB0 = mk8h(Wih_e, Whh_e, vB, oB, scB, kt * 8);
    aB1 = mk8h(Wih_e, Whh_e, vB, oB, scB, 32 + kt * 8);
    aC0 = mk8h(Wih_e, Whh_e, vC, oC, scC, kt * 8);
    aC1 = mk8h(Wih_e, Whh_e, vC, oC, scC, 32 + kt * 8);
    aD0 = mk8h(Wih_e, Whh_e, vD, oD, scD, kt * 8);
    aD1 = mk8h(Wih_e, Whh_e, vD, oD, scD, 32 + kt * 8);

    // xstage chunk for steps 0..15
    for (int idx = tid; idx < ROWS * 96; idx += BLK) {
        int row = idx / 96, cc = idx - row * 96;
        xs[row * 97 + cc] = seq[(size_t)(b0 + row) * SEQ_STRIDE + cc];
    }
    __syncthreads();

    // prologue: x_0 into buf0 (h-slots already zero = h0)
    if (tid < 96) {
        int row = tid & 15, n = tid >> 4;
        BhU[row * 8 + n] = h_bits((_Float16)xs[row * 97 + n]);
    }
    __syncthreads();

    float cA = 0.0f, cB = 0.0f, cC = 0.0f, cD = 0.0f;

    for (int t = 0; t < SS + TT; ++t) {
        const int P = t & 1, Q = P ^ 1;
        const int Pofs8 = P * 128;          // half8 offset of read buffer
        unsigned short* BhQ = BhU + Q * 1024;

        if (t == SS) {
            // switch to decoder weights; prior reads fenced by end barrier of SS-1
            aA0 = mk8h(Wih_d, Whh_d, vA, oA, scA, kt * 8);
            aA1 = mk8h(Wih_d, Whh_d, vA, oA, scA, 32 + kt * 8);
            aB0 = mk8h(Wih_d, Whh_d, vB, oB, scB, kt * 8);
            aB1 = mk8h(Wih_d, Whh_d, vB, oB, scB, 32 + kt * 8);
            aC0 = mk8h(Wih_d, Whh_d, vC, oC, scC, kt * 8);
            aC1 = mk8h(Wih_d, Whh_d, vC, oC, scC, 32 + kt * 8);
            aD0 = mk8h(Wih_d, Whh_d, vD, oD, scD, kt * 8);
            aD1 = mk8h(Wih_d, Whh_d, vD, oD, scD, 32 + kt * 8);
            for (int g2 = tid; g2 < 256; g2 += BLK) {
                int u = g2 >> 2, gt = g2 & 3;
                float sc = (gt == 2) ? -2.0f * LOG2E : -LOG2E;
                bs[g2] = (u < HH) ? sc * (bih_d[gt * HH + u] + bhh_d[gt * HH + u]) : 0.0f;
            }
            __syncthreads();
        }
        if ((t & 15) == 15 && t < SS - 1) {
            // refresh xs for steps t+1 .. t+16 (prev reads done at end barrier)
            const int t0 = t + 1;
            for (int idx = tid; idx < ROWS * 96; idx += BLK) {
                int row = idx / 96, cc = idx - row * 96;
                float v = 0.0f;
                if (t0 + cc / 6 < SS)
                    v = seq[(size_t)(b0 + row) * SEQ_STRIDE + t0 * NF + cc];
                xs[row * 97 + cc] = v;
            }
            __syncthreads();
        }

        // ---- MFMA: acc starts at pre-scaled bias (broadcast ds_read_b128) ----
        f32x4 accA = *(const f32x4*)&bs[tA * 16 + q * 4];
        f32x4 accB = *(const f32x4*)&bs[tB * 16 + q * 4];
        f32x4 accC = *(const f32x4*)&bs[tC * 16 + q * 4];
        f32x4 accD = hasD ? *(const f32x4*)&bs[tD * 16 + q * 4]
                          : (f32x4){0.f, 0.f, 0.f, 0.f};
        {
            half8 bh0 = Bh8[Pofs8 + lane];
            accA = __builtin_amdgcn_mfma_f32_16x16x32_f16(aA0, bh0, accA, 0, 0, 0);
            accB = __builtin_amdgcn_mfma_f32_16x16x32_f16(aB0, bh0, accB, 0, 0, 0);
            accC = __builtin_amdgcn_mfma_f32_16x16x32_f16(aC0, bh0, accC, 0, 0, 0);
            if (hasD) accD = __builtin_amdgcn_mfma_f32_16x16x32_f16(aD0, bh0, accD, 0, 0, 0);
            half8 bh1 = Bh8[Pofs8 + 64 + lane];
            accA = __builtin_amdgcn_mfma_f32_16x16x32_f16(aA1, bh1, accA, 0, 0, 0);
            accB = __builtin_amdgcn_mfma_f32_16x16x32_f16(aB1, bh1, accB, 0, 0, 0);
            accC = __builtin_amdgcn_mfma_f32_16x16x32_f16(aC1, bh1, accC, 0, 0, 0);
            if (hasD) accD = __builtin_amdgcn_mfma_f32_16x16x32_f16(aD1, bh1, accD, 0, 0, 0);
        }

        // ---- write x_{t+1} into Q (encoder source; t==SS-1 writes dec_in) ----
        if (t < SS && tid < 96) {
            int row = tid & 15, n = tid >> 4;
            int px = (t + 1 < SS) ? t + 1 : SS - 1;
            BhQ[row * 8 + n] = h_bits((_Float16)xs[row * 97 + (px & 15) * NF + n]);
        }

        // ---- lane-local cell update; h_t (fp16) into Q ----
        cell_upd(accA, cA, rA, posA, BhQ);
        cell_upd(accB, cB, rB, posB, BhQ);
        cell_upd(accC, cC, rC, posC, BhQ);
        if (hasD) cell_upd(accD, cD, rD, posD, BhQ);

        // ---- decoder: pred from h_t (needs barrier), feed back as x_{t+1} ----
        if (t >= SS) {
            __syncthreads();   // h_t visible in Q
            if (tid < 96) {
                int row = tid & 15, n = tid >> 4;
                float a = bls[n];
                #pragma unroll
                for (int u2 = 0; u2 < HH; ++u2) {
                    int k = NF + u2;
                    int pos = ((k >> 5) * 64 + ((k >> 3) & 3) * 16 + row) * 8 + (k & 7);
                    a = fmaf(Wls[n * HH + u2], h_f(BhQ[pos]), a);
                }
                out[(size_t)(b0 + row) * (TT * NF) + (t - SS) * NF + n] = a;
                BhQ[row * 8 + n] = h_bits((_Float16)a);
            }
        }

        __syncthreads();       // Q complete; P free for reuse next step
    }
}

extern "C" void kernel_launch(void* const* d_in, const int* in_sizes, int n_in,
                              void* d_out, int out_size, void* d_ws, size_t ws_size,
                              hipStream_t stream)
{
    const float* seq   = (const float*)d_in[0];
    const float* Wih_e = (const float*)d_in[1];
    const float* Whh_e = (const float*)d_in[2];
    const float* bih_e = (const float*)d_in[3];
    const float* bhh_e = (const float*)d_in[4];
    const float* Wih_d = (const float*)d_in[5];
    const float* Whh_d = (const float*)d_in[6];
    const float* bih_d = (const float*)d_in[7];
    const float* bhh_d = (const float*)d_in[8];
    const float* Wl    = (const float*)d_in[9];
    const float* bl    = (const float*)d_in[10];
    float* out = (float*)d_out;

    dim3 grid(BB / ROWS);   // 1024 blocks -> 4 per CU, single pass
    dim3 block(BLK);        // 4 waves
    lstm_mfma9<<<grid, block, 0, stream>>>(seq, Wih_e, Whh_e, bih_e, bhh_e,
                                           Wih_d, Whh_d, bih_d, bhh_d,
                                           Wl, bl, out);
}

// Round 12
// 278.890 us; speedup vs baseline: 6.4276x; 1.0279x over previous
//
#include <hip/hip_runtime.h>

#define BB 16384
#define SS 200
#define NF 6
#define HH 50
#define TT 5
#define ROWS 16
#define BLK 512
#define SEQ_STRIDE (SS * NF)   // 1200

typedef _Float16 half8 __attribute__((ext_vector_type(8)));
typedef __attribute__((ext_vector_type(4))) float f32x4;

#define LOG2E 1.44269504088896f

__device__ __forceinline__ unsigned short h_bits(_Float16 h) {
    return __builtin_bit_cast(unsigned short, h);
}
__device__ __forceinline__ float h_f(unsigned short b) {
    return (float)__builtin_bit_cast(_Float16, b);
}

// Weight fragment for 8 consecutive k of one A-row, PRE-SCALED so the MFMA
// output is directly the exp2 argument:
//   gates i,f,o: s = -log2e * gate   -> sigma = rcp(1+exp2(s))
//   gate  g    : s = -2log2e * g     -> tanh  = 2*rcp(1+exp2(s)) - 1
__device__ __forceinline__ half8 mk8h(const float* __restrict__ Wih,
                                      const float* __restrict__ Whh,
                                      bool valid, int orow, float rscale, int kbase)
{
    half8 r;
    #pragma unroll
    for (int j = 0; j < 8; ++j) {
        int k = kbase + j;
        float v = 0.0f;
        if (valid && k < NF + HH)
            v = (k < NF) ? Wih[orow * NF + k] : Whh[orow * HH + (k - NF)];
        r[j] = (_Float16)(v * rscale);
    }
    return r;
}

// Pre-scaled cell update; stores h (fp16) at precomputed offset posQ.
__device__ __forceinline__ void cell_upd(const f32x4& g, float& c, bool real,
                                         int posQ, unsigned short* BhQ)
{
    float si = __builtin_amdgcn_rcpf(1.0f + __builtin_amdgcn_exp2f(g[0]));
    float sf = __builtin_amdgcn_rcpf(1.0f + __builtin_amdgcn_exp2f(g[1]));
    float tg = fmaf(2.0f, __builtin_amdgcn_rcpf(1.0f + __builtin_amdgcn_exp2f(g[2])), -1.0f);
    float so = __builtin_amdgcn_rcpf(1.0f + __builtin_amdgcn_exp2f(g[3]));
    float cc = sf * c + si * tg;
    c = cc;
    float tc = fmaf(2.0f, __builtin_amdgcn_rcpf(1.0f +
                    __builtin_amdgcn_exp2f(-2.0f * LOG2E * cc)), -1.0f);
    float hh = so * tc;
    if (real) BhQ[posQ] = h_bits((_Float16)hh);
}

__global__ __launch_bounds__(BLK, 8) void lstm_mfma10(
    const float* __restrict__ seq,
    const float* __restrict__ Wih_e, const float* __restrict__ Whh_e,
    const float* __restrict__ bih_e, const float* __restrict__ bhh_e,
    const float* __restrict__ Wih_d, const float* __restrict__ Whh_d,
    const float* __restrict__ bih_d, const float* __restrict__ bhh_d,
    const float* __restrict__ Wl, const float* __restrict__ bl,
    float* __restrict__ out)
{
    __shared__ half8 Bh8[256];              // 2 buffers x 128 chunks (4KB)
    __shared__ float bs[256];               // fused pre-scaled bias, g2 order
    __shared__ float xs[ROWS * 97];         // 16 steps x 6 feats per row
    __shared__ float Wls[NF * HH];
    __shared__ float bls[NF];

    unsigned short* BhU = (unsigned short*)Bh8;   // buffer P at ushort ofs P*1024

    const int tid  = threadIdx.x;
    const int w    = tid >> 6;              // 8 waves
    const int lane = tid & 63;
    const int q    = lane >> 4;
    const int l15  = lane & 15;
    const int b0   = blockIdx.x * ROWS;
    // M-tiles: wave w owns {w} and, for w<5, {w+8}  (13 real tiles)
    const int tA = w, tB = w + 8;
    const bool hasB = (w < 5);

    // per-lane A-row descriptors (lane kt*16+r holds A[mt*16+r][ks*32+kt*8+j])
    const int r15 = lane & 15, kt = lane >> 4;
    const int g2A = tA * 16 + r15, uAr = g2A >> 2;
    const int g2B = tB * 16 + r15, uBr = g2B >> 2;
    const bool vA = (uAr < HH);
    const bool vB = hasB && (uBr < HH);
    const int oA = (g2A & 3) * HH + uAr, oB = (g2B & 3) * HH + uBr;
    const float scA = ((g2A & 3) == 2) ? -2.0f * LOG2E : -LOG2E;
    const float scB = ((g2B & 3) == 2) ? -2.0f * LOG2E : -LOG2E;

    // per-lane h-store offsets (unit -> B slot), hoisted out of the t-loop
    const int uA = tA * 4 + q, uB = tB * 4 + q;
    #define HPOS(u) (((((NF + (u)) >> 5) * 64) + (((NF + (u)) >> 3) & 3) * 16 + l15) * 8 + ((NF + (u)) & 7))
    const int posA = HPOS(uA), posB = HPOS(uB);
    const bool rA = (uA < HH);
    const bool rB = hasB && (uB < HH);

    // ---- one-time init ----
    {
        unsigned* zh = (unsigned*)Bh8;
        for (int i = tid; i < 1024; i += BLK) zh[i] = 0u;
    }
    for (int i = tid; i < NF * HH; i += BLK) Wls[i] = Wl[i];
    if (tid < NF) bls[tid] = bl[tid];
    for (int g2 = tid; g2 < 256; g2 += BLK) {
        int u = g2 >> 2, gt = g2 & 3;
        float sc = (gt == 2) ? -2.0f * LOG2E : -LOG2E;
        bs[g2] = (u < HH) ? sc * (bih_e[gt * HH + u] + bhh_e[gt * HH + u]) : 0.0f;
    }

    half8 aA0, aA1, aB0, aB1;
    aA0 = mk8h(Wih_e, Whh_e, vA, oA, scA, kt * 8);
    aA1 = mk8h(Wih_e, Whh_e, vA, oA, scA, 32 + kt * 8);
    aB0 = mk8h(Wih_e, Whh_e, vB, oB, scB, kt * 8);
    aB1 = mk8h(Wih_e, Whh_e, vB, oB, scB, 32 + kt * 8);

    // xstage chunk for steps 0..15
    for (int idx = tid; idx < ROWS * 96; idx += BLK) {
        int row = idx / 96, cc = idx - row * 96;
        xs[row * 97 + cc] = seq[(size_t)(b0 + row) * SEQ_STRIDE + cc];
    }
    __syncthreads();

    // prologue: x_0 into buf0 (h-slots already zero = h0)
    if (tid < 96) {
        int row = tid & 15, n = tid >> 4;
        BhU[row * 8 + n] = h_bits((_Float16)xs[row * 97 + n]);
    }
    __syncthreads();

    float cA = 0.0f, cB = 0.0f;

    for (int t = 0; t < SS + TT; ++t) {
        const int P = t & 1, Q = P ^ 1;
        const int Pofs8 = P * 128;          // half8 offset of read buffer
        unsigned short* BhQ = BhU + Q * 1024;

        if (t == SS) {
            // switch to decoder weights; prior reads fenced by end barrier of SS-1
            aA0 = mk8h(Wih_d, Whh_d, vA, oA, scA, kt * 8);
            aA1 = mk8h(Wih_d, Whh_d, vA, oA, scA, 32 + kt * 8);
            aB0 = mk8h(Wih_d, Whh_d, vB, oB, scB, kt * 8);
            aB1 = mk8h(Wih_d, Whh_d, vB, oB, scB, 32 + kt * 8);
            for (int g2 = tid; g2 < 256; g2 += BLK) {
                int u = g2 >> 2, gt = g2 & 3;
                float sc = (gt == 2) ? -2.0f * LOG2E : -LOG2E;
                bs[g2] = (u < HH) ? sc * (bih_d[gt * HH + u] + bhh_d[gt * HH + u]) : 0.0f;
            }
            __syncthreads();
        }
        if ((t & 15) == 15 && t < SS - 1) {
            // refresh xs for steps t+1 .. t+16 (prev reads done at end barrier)
            const int t0 = t + 1;
            for (int idx = tid; idx < ROWS * 96; idx += BLK) {
                int row = idx / 96, cc = idx - row * 96;
                float v = 0.0f;
                if (t0 + cc / 6 < SS)
                    v = seq[(size_t)(b0 + row) * SEQ_STRIDE + t0 * NF + cc];
                xs[row * 97 + cc] = v;
            }
            __syncthreads();
        }

        // ---- MFMA: acc starts at pre-scaled bias (broadcast ds_read_b128) ----
        f32x4 accA = *(const f32x4*)&bs[tA * 16 + q * 4];
        f32x4 accB = hasB ? *(const f32x4*)&bs[tB * 16 + q * 4]
                          : (f32x4){0.f, 0.f, 0.f, 0.f};
        {
            half8 bh0 = Bh8[Pofs8 + lane];
            accA = __builtin_amdgcn_mfma_f32_16x16x32_f16(aA0, bh0, accA, 0, 0, 0);
            if (hasB) accB = __builtin_amdgcn_mfma_f32_16x16x32_f16(aB0, bh0, accB, 0, 0, 0);
            half8 bh1 = Bh8[Pofs8 + 64 + lane];
            accA = __builtin_amdgcn_mfma_f32_16x16x32_f16(aA1, bh1, accA, 0, 0, 0);
            if (hasB) accB = __builtin_amdgcn_mfma_f32_16x16x32_f16(aB1, bh1, accB, 0, 0, 0);
        }

        // ---- write x_{t+1} into Q (encoder source; t==SS-1 writes dec_in) ----
        if (t < SS && tid < 96) {
            int row = tid & 15, n = tid >> 4;
            int px = (t + 1 < SS) ? t + 1 : SS - 1;
            BhQ[row * 8 + n] = h_bits((_Float16)xs[row * 97 + (px & 15) * NF + n]);
        }

        // ---- lane-local cell update; h_t (fp16) into Q ----
        cell_upd(accA, cA, rA, posA, BhQ);
        if (hasB) cell_upd(accB, cB, rB, posB, BhQ);

        // ---- decoder: pred from h_t (needs barrier), feed back as x_{t+1} ----
        if (t >= SS) {
            __syncthreads();   // h_t visible in Q
            if (tid < 96) {
                int row = tid & 15, n = tid >> 4;
                float a = bls[n];
                #pragma unroll
                for (int u2 = 0; u2 < HH; ++u2) {
                    int k = NF + u2;
                    int pos = ((k >> 5) * 64 + ((k >> 3) & 3) * 16 + row) * 8 + (k & 7);
                    a = fmaf(Wls[n * HH + u2], h_f(BhQ[pos]), a);
                }
                out[(size_t)(b0 + row) * (TT * NF) + (t - SS) * NF + n] = a;
                BhQ[row * 8 + n] = h_bits((_Float16)a);
            }
        }

        __syncthreads();       // Q complete; P free for reuse next step
    }
}

extern "C" void kernel_launch(void* const* d_in, const int* in_sizes, int n_in,
                              void* d_out, int out_size, void* d_ws, size_t ws_size,
                              hipStream_t stream)
{
    const float* seq   = (const float*)d_in[0];
    const float* Wih_e = (const float*)d_in[1];
    const float* Whh_e = (const float*)d_in[2];
    const float* bih_e = (const float*)d_in[3];
    const float* bhh_e = (const float*)d_in[4];
    const float* Wih_d = (const float*)d_in[5];
    const float* Whh_d = (const float*)d_in[6];
    const float* bih_d = (const float*)d_in[7];
    const float* bhh_d = (const float*)d_in[8];
    const float* Wl    = (const float*)d_in[9];
    const float* bl    = (const float*)d_in[10];
    float* out = (float*)d_out;

    dim3 grid(BB / ROWS);   // 1024 blocks x 8 waves -> 8 waves/SIMD potential
    dim3 block(BLK);
    lstm_mfma10<<<grid, block, 0, stream>>>(seq, Wih_e, Whh_e, bih_e, bhh_e,
                                            Wih_d, Whh_d, bih_d, bhh_d,
                                            Wl, bl, out);
}

// Round 13
// 251.136 us; speedup vs baseline: 7.1380x; 1.1105x over previous
//
#include <hip/hip_runtime.h>

#define BB 16384
#define SS 200
#define NF 6
#define HH 50
#define TT 5
#define ROWS 16
#define BLK 512
#define SEQ_STRIDE (SS * NF)   // 1200

typedef _Float16 half8 __attribute__((ext_vector_type(8)));
typedef __attribute__((ext_vector_type(4))) float f32x4;

#define LOG2E 1.44269504088896f

__device__ __forceinline__ unsigned short h_bits(_Float16 h) {
    return __builtin_bit_cast(unsigned short, h);
}
__device__ __forceinline__ float h_f(unsigned short b) {
    return (float)__builtin_bit_cast(_Float16, b);
}

// Weight fragment for 8 consecutive k of one A-row, PRE-SCALED so the MFMA
// output is directly the exp2 argument.
__device__ __forceinline__ half8 mk8h(const float* __restrict__ Wih,
                                      const float* __restrict__ Whh,
                                      bool valid, int orow, float rscale, int kbase)
{
    half8 r;
    #pragma unroll
    for (int j = 0; j < 8; ++j) {
        int k = kbase + j;
        float v = 0.0f;
        if (valid && k < NF + HH)
            v = (k < NF) ? Wih[orow * NF + k] : Whh[orow * HH + (k - NF)];
        r[j] = (_Float16)(v * rscale);
    }
    return r;
}

// Pre-scaled fused bias for unit u: {i,f,g,o} with gate scales applied.
__device__ __forceinline__ f32x4 mkbias(const float* __restrict__ bih,
                                        const float* __restrict__ bhh,
                                        bool valid, int u)
{
    f32x4 b;
    #pragma unroll
    for (int r = 0; r < 4; ++r) {
        float sc = (r == 2) ? -2.0f * LOG2E : -LOG2E;
        b[r] = valid ? sc * (bih[r * HH + u] + bhh[r * HH + u]) : 0.0f;
    }
    return b;
}

// Pre-scaled cell update; stores h (fp16) at precomputed offset posQ.
__device__ __forceinline__ void cell_upd(const f32x4& g, float& c, bool real,
                                         int posQ, unsigned short* BhQ)
{
    float si = __builtin_amdgcn_rcpf(1.0f + __builtin_amdgcn_exp2f(g[0]));
    float sf = __builtin_amdgcn_rcpf(1.0f + __builtin_amdgcn_exp2f(g[1]));
    float tg = fmaf(2.0f, __builtin_amdgcn_rcpf(1.0f + __builtin_amdgcn_exp2f(g[2])), -1.0f);
    float so = __builtin_amdgcn_rcpf(1.0f + __builtin_amdgcn_exp2f(g[3]));
    float cc = sf * c + si * tg;
    c = cc;
    float tc = fmaf(2.0f, __builtin_amdgcn_rcpf(1.0f +
                    __builtin_amdgcn_exp2f(-2.0f * LOG2E * cc)), -1.0f);
    float hh = so * tc;
    if (real) BhQ[posQ] = h_bits((_Float16)hh);
}

#define MFMA16(acc, a, b) acc = __builtin_amdgcn_mfma_f32_16x16x32_f16(a, b, acc, 0, 0, 0)

__global__ __launch_bounds__(BLK, 8) void lstm_mfma11(
    const float* __restrict__ seq,
    const float* __restrict__ Wih_e, const float* __restrict__ Whh_e,
    const float* __restrict__ bih_e, const float* __restrict__ bhh_e,
    const float* __restrict__ Wih_d, const float* __restrict__ Whh_d,
    const float* __restrict__ bih_d, const float* __restrict__ bhh_d,
    const float* __restrict__ Wl, const float* __restrict__ bl,
    float* __restrict__ out)
{
    __shared__ half8 Bh8[256];              // 2 buffers x 128 chunks (4KB)
    __shared__ float xs[ROWS * 97];         // 16 steps x 6 feats per row
    __shared__ float Wls[NF * HH];
    __shared__ float bls[NF];

    unsigned short* BhU = (unsigned short*)Bh8;   // buffer P at ushort ofs P*1024

    const int tid  = threadIdx.x;
    const int w    = tid >> 6;              // 8 waves
    const int lane = tid & 63;
    const int q    = lane >> 4;
    const int l15  = lane & 15;
    const int b0   = blockIdx.x * ROWS;
    // role rotation: distributes the 2-tile waves across SIMDs per block
    const int wr   = (w + (int)blockIdx.x) & 7;
    const int tA = wr, tB = wr + 8;         // 13 real tiles: {0..7} + {8..12}
    const bool hasB = (wr < 5);

    // per-lane A-row descriptors (lane kt*16+r holds A[mt*16+r][ks*32+kt*8+j])
    const int r15 = lane & 15, kt = lane >> 4;
    const int g2A = tA * 16 + r15, uAr = g2A >> 2;
    const int g2B = tB * 16 + r15, uBr = g2B >> 2;
    const bool vA = (uAr < HH);
    const bool vB = hasB && (uBr < HH);
    const int oA = (g2A & 3) * HH + uAr, oB = (g2B & 3) * HH + uBr;
    const float scA = ((g2A & 3) == 2) ? -2.0f * LOG2E : -LOG2E;
    const float scB = ((g2B & 3) == 2) ? -2.0f * LOG2E : -LOG2E;

    // per-lane h-store offsets (unit -> B slot), hoisted out of the t-loop
    const int uA = tA * 4 + q, uB = tB * 4 + q;
    #define HPOS(u) (((((NF + (u)) >> 5) * 64) + (((NF + (u)) >> 3) & 3) * 16 + l15) * 8 + ((NF + (u)) & 7))
    const int posA = HPOS(uA), posB = HPOS(uB);
    const bool rA = (uA < HH);
    const bool rB = hasB && (uB < HH);

    // ---- one-time init ----
    {
        unsigned* zh = (unsigned*)Bh8;
        for (int i = tid; i < 1024; i += BLK) zh[i] = 0u;
    }
    for (int i = tid; i < NF * HH; i += BLK) Wls[i] = Wl[i];
    if (tid < NF) bls[tid] = bl[tid];

    half8 aA0 = mk8h(Wih_e, Whh_e, vA, oA, scA, kt * 8);
    half8 aA1 = mk8h(Wih_e, Whh_e, vA, oA, scA, 32 + kt * 8);
    half8 aB0 = mk8h(Wih_e, Whh_e, vB, oB, scB, kt * 8);
    half8 aB1 = mk8h(Wih_e, Whh_e, vB, oB, scB, 32 + kt * 8);
    f32x4 bA = mkbias(bih_e, bhh_e, rA, uA);
    f32x4 bB = hasB ? mkbias(bih_e, bhh_e, rB, uB) : (f32x4){0.f, 0.f, 0.f, 0.f};

    // xstage chunk for steps 0..15
    for (int idx = tid; idx < ROWS * 96; idx += BLK) {
        int row = idx / 96, cc = idx - row * 96;
        xs[row * 97 + cc] = seq[(size_t)(b0 + row) * SEQ_STRIDE + cc];
    }
    __syncthreads();

    // prologue: x_0 into buf0 (h-slots already zero = h0)
    if (tid < 96) {
        int row = tid & 15, n = tid >> 4;
        BhU[row * 8 + n] = h_bits((_Float16)xs[row * 97 + n]);
    }
    __syncthreads();

    float cA = 0.0f, cB = 0.0f;

    // ==== encoder main: 12 chunks of 16 steps (t = 0..191) ====
    for (int t0 = 0; t0 < 192; t0 += 16) {
        #pragma unroll
        for (int k = 0; k < 16; ++k) {
            const int Pofs8 = (k & 1) * 128;
            unsigned short* BhQ = BhU + ((k & 1) ^ 1) * 1024;

            f32x4 accA = bA;
            f32x4 accB = bB;
            half8 bh0 = Bh8[Pofs8 + lane];
            MFMA16(accA, aA0, bh0);
            if (hasB) MFMA16(accB, aB0, bh0);
            half8 bh1 = Bh8[Pofs8 + 64 + lane];
            MFMA16(accA, aA1, bh1);
            if (hasB) MFMA16(accB, aB1, bh1);

            if (k == 15) {
                // refresh xs for steps t0+16 .. t0+31 (slot s holds step t0+16+s)
                const int tn = t0 + 16;
                for (int idx = tid; idx < ROWS * 96; idx += BLK) {
                    int row = idx / 96, cc = idx - row * 96;
                    float v = 0.0f;
                    if (tn + cc / 6 < SS)
                        v = seq[(size_t)(b0 + row) * SEQ_STRIDE + tn * NF + cc];
                    xs[row * 97 + cc] = v;
                }
                __syncthreads();   // new chunk visible before x-write reads slot 0
            }
            // write x_{t+1} (compile-time slot) into Q
            if (tid < 96) {
                int row = tid & 15, n = tid >> 4;
                BhQ[row * 8 + n] =
                    h_bits((_Float16)xs[row * 97 + (((k + 1) & 15)) * NF + n]);
            }
            cell_upd(accA, cA, rA, posA, BhQ);
            if (hasB) cell_upd(accB, cB, rB, posB, BhQ);
            __syncthreads();
        }
    }

    // ==== encoder tail: t = 192..199 (xs slots 0..7 staged in last chunk) ====
    #pragma unroll
    for (int k = 0; k < 8; ++k) {
        const int Pofs8 = (k & 1) * 128;
        unsigned short* BhQ = BhU + ((k & 1) ^ 1) * 1024;

        f32x4 accA = bA;
        f32x4 accB = bB;
        half8 bh0 = Bh8[Pofs8 + lane];
        MFMA16(accA, aA0, bh0);
        if (hasB) MFMA16(accB, aB0, bh0);
        half8 bh1 = Bh8[Pofs8 + 64 + lane];
        MFMA16(accA, aA1, bh1);
        if (hasB) MFMA16(accB, aB1, bh1);

        // x_{t+1}; at k==7 (t=199) write dec_in = x_{199} (slot 7)
        const int slot = (k < 7) ? (k + 1) : 7;
        if (tid < 96) {
            int row = tid & 15, n = tid >> 4;
            BhQ[row * 8 + n] = h_bits((_Float16)xs[row * 97 + slot * NF + n]);
        }
        cell_upd(accA, cA, rA, posA, BhQ);
        if (hasB) cell_upd(accB, cB, rB, posB, BhQ);
        __syncthreads();
    }

    // ==== switch to decoder weights (registers only; no barrier needed) ====
    aA0 = mk8h(Wih_d, Whh_d, vA, oA, scA, kt * 8);
    aA1 = mk8h(Wih_d, Whh_d, vA, oA, scA, 32 + kt * 8);
    aB0 = mk8h(Wih_d, Whh_d, vB, oB, scB, kt * 8);
    aB1 = mk8h(Wih_d, Whh_d, vB, oB, scB, 32 + kt * 8);
    bA = mkbias(bih_d, bhh_d, rA, uA);
    if (hasB) bB = mkbias(bih_d, bhh_d, rB, uB);

    // ==== decoder: t = 200..204 (t even at k=0 -> P = k&1) ====
    #pragma unroll
    for (int k = 0; k < TT; ++k) {
        const int Pofs8 = (k & 1) * 128;
        unsigned short* BhQ = BhU + ((k & 1) ^ 1) * 1024;

        f32x4 accA = bA;
        f32x4 accB = bB;
        half8 bh0 = Bh8[Pofs8 + lane];
        MFMA16(accA, aA0, bh0);
        if (hasB) MFMA16(accB, aB0, bh0);
        half8 bh1 = Bh8[Pofs8 + 64 + lane];
        MFMA16(accA, aA1, bh1);
        if (hasB) MFMA16(accB, aB1, bh1);

        cell_upd(accA, cA, rA, posA, BhQ);
        if (hasB) cell_upd(accB, cB, rB, posB, BhQ);
        __syncthreads();   // h_t visible in Q

        if (tid < 96) {
            int row = tid & 15, n = tid >> 4;
            float a = bls[n];
            #pragma unroll
            for (int u2 = 0; u2 < HH; ++u2) {
                int kk = NF + u2;
                int pos = ((kk >> 5) * 64 + ((kk >> 3) & 3) * 16 + row) * 8 + (kk & 7);
                a = fmaf(Wls[n * HH + u2], h_f(BhQ[pos]), a);
            }
            out[(size_t)(b0 + row) * (TT * NF) + k * NF + n] = a;
            BhQ[row * 8 + n] = h_bits((_Float16)a);   // feed back as next x
        }
        __syncthreads();
    }
}

extern "C" void kernel_launch(void* const* d_in, const int* in_sizes, int n_in,
                              void* d_out, int out_size, void* d_ws, size_t ws_size,
                              hipStream_t stream)
{
    const float* seq   = (const float*)d_in[0];
    const float* Wih_e = (const float*)d_in[1];
    const float* Whh_e = (const float*)d_in[2];
    const float* bih_e = (const float*)d_in[3];
    const float* bhh_e = (const float*)d_in[4];
    const float* Wih_d = (const float*)d_in[5];
    const float* Whh_d = (const float*)d_in[6];
    const float* bih_d = (const float*)d_in[7];
    const float* bhh_d = (const float*)d_in[8];
    const float* Wl    = (const float*)d_in[9];
    const float* bl    = (const float*)d_in[10];
    float* out = (float*)d_out;

    dim3 grid(BB / ROWS);   // 1024 blocks -> 4 per CU
    dim3 block(BLK);        // 8 waves
    lstm_mfma11<<<grid, block, 0, stream>>>(seq, Wih_e, Whh_e, bih_e, bhh_e,
                                            Wih_d, Whh_d, bih_d, bhh_d,
                                            Wl, bl, out);
}